// Round 2
// baseline (15329.245 us; speedup 1.0000x reference)
//
#include <hip/hip_runtime.h>

constexpr int B  = 64;
constexpr int T  = 121;
constexpr int E  = 300;
constexpr int H  = 256;
constexpr int G4 = 1024;   // 4*H
constexpr int D  = 512;    // 2*H
constexpr int NH = 3;
constexpr int BT = B * T;  // 7744

__device__ __forceinline__ float sigmoidf(float x) { return 1.0f / (1.0f + __expf(-x)); }
__device__ __forceinline__ float tanhf_fast(float x) {
  float e = __expf(2.0f * x);
  return 1.0f - 2.0f / (e + 1.0f);
}

// ---------------- embedding gather ----------------
__global__ void k_gather(const int* __restrict__ tokens, const float* __restrict__ emb,
                         float* __restrict__ x) {
  int bt = blockIdx.x;
  int tok = tokens[bt];
  const float* src = emb + (size_t)tok * E;
  float* dst = x + (size_t)bt * E;
  for (int e = threadIdx.x; e < E; e += blockDim.x) dst[e] = src[e];
}

// ---------------- generic fp32 GEMM: C = A@W (+bias) (+Cin) ----------------
__global__ __launch_bounds__(256) void k_gemm(
    const float* __restrict__ A, const float* __restrict__ W,
    const float* __restrict__ bias, const float* __restrict__ Cin,
    float* __restrict__ C, int M, int N, int K)
{
  __shared__ float As[16][68];
  __shared__ float Ws[16][68];
  int tid = threadIdx.x;
  int tx = tid & 15, ty = tid >> 4;
  int row0 = blockIdx.y * 64, col0 = blockIdx.x * 64;
  float acc[4][4] = {};
  for (int k0 = 0; k0 < K; k0 += 16) {
#pragma unroll
    for (int i = 0; i < 4; ++i) {
      int idx = tid + i * 256;
      int kk = idx & 15, r = idx >> 4;
      int gk = k0 + kk;
      As[kk][r] = (gk < K) ? A[(size_t)(row0 + r) * K + gk] : 0.0f;
    }
#pragma unroll
    for (int i = 0; i < 4; ++i) {
      int idx = tid + i * 256;
      int c = idx & 63, kk = idx >> 6;
      int gk = k0 + kk, gc = col0 + c;
      Ws[kk][c] = (gk < K && gc < N) ? W[(size_t)gk * N + gc] : 0.0f;
    }
    __syncthreads();
#pragma unroll
    for (int k = 0; k < 16; ++k) {
      float4 av = *reinterpret_cast<const float4*>(&As[k][ty * 4]);
      float4 wv = *reinterpret_cast<const float4*>(&Ws[k][tx * 4]);
      float a4[4] = {av.x, av.y, av.z, av.w};
      float w4[4] = {wv.x, wv.y, wv.z, wv.w};
#pragma unroll
      for (int i = 0; i < 4; ++i)
#pragma unroll
        for (int j = 0; j < 4; ++j)
          acc[i][j] = fmaf(a4[i], w4[j], acc[i][j]);
    }
    __syncthreads();
  }
#pragma unroll
  for (int i = 0; i < 4; ++i) {
    int gr = row0 + ty * 4 + i;
#pragma unroll
    for (int j = 0; j < 4; ++j) {
      int gc = col0 + tx * 4 + j;
      if (gc < N) {
        float v = acc[i][j];
        if (bias) v += bias[gc];
        if (Cin)  v += Cin[(size_t)gr * N + gc];
        C[(size_t)gr * N + gc] = v;
      }
    }
  }
}

// ---------------- BiLSTM scan (unchanged this round) ----------------
__global__ __launch_bounds__(256) void k_lstm(
    const float* __restrict__ xp_f, const float* __restrict__ xp_b,
    const float* __restrict__ Wh_f, const float* __restrict__ Wh_b,
    const int* __restrict__ lengths, float* __restrict__ facts)
{
  int b = blockIdx.x;
  int dir = blockIdx.y;
  const float* xp = dir ? xp_b : xp_f;
  const float* Wh = dir ? Wh_b : Wh_f;
  int j = threadIdx.x;
  __shared__ float hs[H];
  hs[j] = 0.0f;
  float c = 0.0f, h = 0.0f;
  int nsteps = dir ? T : lengths[b];
  __syncthreads();
  for (int s = 0; s < nsteps; ++s) {
    int t = dir ? (T - 1 - s) : s;
    const float* xrow = xp + (size_t)(b * T + t) * G4;
    float g0 = xrow[j], g1 = xrow[j + 256], g2 = xrow[j + 512], g3 = xrow[j + 768];
#pragma unroll 4
    for (int k = 0; k < H; ++k) {
      float hv = hs[k];
      const float* w = Wh + (size_t)k * G4 + j;
      g0 = fmaf(hv, w[0],   g0);
      g1 = fmaf(hv, w[256], g1);
      g2 = fmaf(hv, w[512], g2);
      g3 = fmaf(hv, w[768], g3);
    }
    float ig = sigmoidf(g0);
    float fg = sigmoidf(g1);
    float gg = tanhf_fast(g2);
    float og = sigmoidf(g3);
    c = fg * c + ig * gg;
    h = og * tanhf_fast(c);
    __syncthreads();
    hs[j] = h;
    facts[(size_t)(b * T + t) * D + dir * H + j] = h;
    __syncthreads();
  }
}

// ---------------- z halves ----------------
__global__ void k_buildz(const float* __restrict__ facts, const float* __restrict__ v,
                         float* __restrict__ za, float* __restrict__ zb) {
  int bt = blockIdx.x;
  int b = bt / T;
  const float* F = facts + (size_t)bt * D;
  const float* vb = v + (size_t)b * D;
  for (int d = threadIdx.x; d < D; d += blockDim.x) {
    float f = F[d], vv = vb[d];
    za[(size_t)bt * D + d] = f * vv;
    zb[(size_t)bt * D + d] = fabsf(f - vv);
  }
}

// ---------------- score ----------------
__global__ void k_score(const float* __restrict__ att_h, const float* __restrict__ W2,
                        const float* __restrict__ b2, float* __restrict__ s) {
  int bt = blockIdx.x;
  int tid = threadIdx.x;  // 64
  float acc = 0.f;
  for (int e = tid; e < E; e += 64)
    acc += tanhf_fast(att_h[(size_t)bt * E + e]) * W2[e];
  for (int off = 32; off > 0; off >>= 1) acc += __shfl_down(acc, off);
  if (tid == 0) s[bt] = acc + b2[0];
}

// ---------------- masked softmax ----------------
__global__ void k_softmax(const float* __restrict__ s, const int* __restrict__ lengths,
                          float* __restrict__ a) {
  int b = blockIdx.x;
  int t = threadIdx.x;  // 128
  int len = lengths[b];
  __shared__ float wred[2];
  float val = -1e30f;
  if (t < T) val = (t < len) ? s[b * T + t] : -1e9f;
  float mx = val;
  for (int off = 32; off > 0; off >>= 1) mx = fmaxf(mx, __shfl_xor(mx, off));
  int wid = t >> 6, lane = t & 63;
  if (lane == 0) wred[wid] = mx;
  __syncthreads();
  mx = fmaxf(wred[0], wred[1]);
  __syncthreads();
  float e = (t < T && t < len) ? __expf(val - mx) : 0.0f;
  float sum = e;
  for (int off = 32; off > 0; off >>= 1) sum += __shfl_xor(sum, off);
  if (lane == 0) wred[wid] = sum;
  __syncthreads();
  float tot = wred[0] + wred[1];
  if (t < T) a[b * T + t] = e / tot;
}

// ---------------- counter zero ----------------
__global__ void k_zero(int* __restrict__ p, int n) {
  int i = blockIdx.x * blockDim.x + threadIdx.x;
  if (i < n) p[i] = 0;
}

// ---------------- device-scope grid barrier ----------------
__device__ __forceinline__ void gbar(int* cnt, int target) {
  __syncthreads();
  if (threadIdx.x == 0) {
    __threadfence();               // release: make our H-slice writes visible
    atomicAdd(cnt, 1);             // device scope by default on CDNA
    while (__hip_atomic_load(cnt, __ATOMIC_RELAXED, __HIP_MEMORY_SCOPE_AGENT) < target)
      __builtin_amdgcn_s_sleep(1);
  }
  __syncthreads();
  __threadfence();                 // acquire: invalidate caches before reading H
}

// ---------------- persistent column-parallel attention GRU ----------------
// 64 blocks x 512 threads. Block bi owns columns j in [bi*8, bi*8+8) of BOTH
// R (= H@Ur) and C (= H@Uc). Per step: slice GEMM -> k-half reduce in LDS ->
// gate update for owned columns (h in registers) -> write H slice -> barrier.
// att==0 exactly for t>=len freezes h (matches reference's full-T scan).
__global__ __launch_bounds__(512) void k_gru_persist(
    const float* __restrict__ xr, const float* __restrict__ xc,
    const float* __restrict__ Ur, const float* __restrict__ Uc,
    const float* __restrict__ br, const float* __restrict__ bc,
    const float* __restrict__ att, float* __restrict__ Hbuf,  // [2][B][D]
    int* __restrict__ syncA, float* __restrict__ ep)
{
  const int bi  = blockIdx.x;        // 0..63
  const int tid = threadIdx.x;
  const int jj   = tid & 7;
  const int half = (tid >> 3) & 1;   // k-range split
  const int bg   = tid >> 4;         // 0..31 -> batches {2bg, 2bg+1}
  const int b0 = bg * 2, b1 = b0 + 1;
  const int j  = bi * 8 + jj;

  __shared__ float red[512][4];      // 8 KB

  // zero our slice of Hbuf[0] (state before step 0)
  {
    int zb_ = tid >> 3;              // 0..63
    Hbuf[zb_ * D + j] = 0.0f;
  }
  gbar(syncA + T, B);                // pre-barrier (slot T)

  float h0 = 0.f, h1 = 0.f;
  const float brj = br[j], bcj = bc[j];

  for (int t = 0; t < T; ++t) {
    const float* Hc = Hbuf + (size_t)(t & 1) * (B * D);
    const float* pH0 = Hc + b0 * D + half * 256;
    const float* pH1 = Hc + b1 * D + half * 256;
    const float* pUr = Ur + (size_t)(half * 256) * D + j;
    const float* pUc = Uc + (size_t)(half * 256) * D + j;
    float ar0 = 0.f, ar1 = 0.f, ac0 = 0.f, ac1 = 0.f;
#pragma unroll 2
    for (int k4 = 0; k4 < 256; k4 += 4) {
      float4 hva = *reinterpret_cast<const float4*>(&pH0[k4]);
      float4 hvb = *reinterpret_cast<const float4*>(&pH1[k4]);
      float ha[4] = {hva.x, hva.y, hva.z, hva.w};
      float hb[4] = {hvb.x, hvb.y, hvb.z, hvb.w};
#pragma unroll
      for (int u = 0; u < 4; ++u) {
        float ur = pUr[(size_t)(k4 + u) * D];
        float uc = pUc[(size_t)(k4 + u) * D];
        ar0 = fmaf(ha[u], ur, ar0);
        ar1 = fmaf(hb[u], ur, ar1);
        ac0 = fmaf(ha[u], uc, ac0);
        ac1 = fmaf(hb[u], uc, ac1);
      }
    }
    red[tid][0] = ar0; red[tid][1] = ar1; red[tid][2] = ac0; red[tid][3] = ac1;
    __syncthreads();
    if (half == 0) {
      int p = tid ^ 8;
      ar0 += red[p][0]; ar1 += red[p][1]; ac0 += red[p][2]; ac1 += red[p][3];
      float g0 = att[b0 * T + t], g1 = att[b1 * T + t];
      size_t i0 = (size_t)(b0 * T + t) * D + j;
      size_t i1 = (size_t)(b1 * T + t) * D + j;
      float r0 = sigmoidf(xr[i0] + ar0 + brj);
      float r1 = sigmoidf(xr[i1] + ar1 + brj);
      float hc0 = tanhf_fast(xc[i0] + r0 * ac0 + bcj);
      float hc1 = tanhf_fast(xc[i1] + r1 * ac1 + bcj);
      h0 = g0 * hc0 + (1.f - g0) * h0;
      h1 = g1 * hc1 + (1.f - g1) * h1;
      float* Hn = Hbuf + (size_t)((t + 1) & 1) * (B * D);
      Hn[b0 * D + j] = h0;
      Hn[b1 * D + j] = h1;
    }
    gbar(syncA + t, B);
  }
  if (half == 0) {
    ep[b0 * D + j] = h0;
    ep[b1 * D + j] = h1;
  }
}

// ---------------- hop projection ----------------
__global__ __launch_bounds__(512) void k_hop(
    const float* __restrict__ m_in, const float* __restrict__ ep,
    const float* __restrict__ q, const float* __restrict__ Whop,
    const float* __restrict__ bhop, float* __restrict__ m_out)
{
  int b = blockIdx.x, j = threadIdx.x;
  __shared__ float av[3 * D];
  av[j]         = m_in[(size_t)b * D + j];
  av[D + j]     = ep[(size_t)b * D + j];
  av[2 * D + j] = q[(size_t)b * D + j];
  __syncthreads();
  float acc = bhop[j];
#pragma unroll 4
  for (int k = 0; k < 3 * D; ++k)
    acc = fmaf(av[k], Whop[(size_t)k * D + j], acc);
  m_out[(size_t)b * D + j] = fmaxf(acc, 0.0f);
}

// ---------------- output ----------------
__global__ void k_out(const float* __restrict__ m, const float* __restrict__ q,
                      const float* __restrict__ Wo, const float* __restrict__ bo,
                      float* __restrict__ out)
{
  int b = blockIdx.x, tid = threadIdx.x;  // 256
  float acc = 0.f;
  for (int k = tid; k < D; k += 256)
    acc += m[(size_t)b * D + k] * Wo[k] + q[(size_t)b * D + k] * Wo[D + k];
  for (int off = 32; off > 0; off >>= 1) acc += __shfl_down(acc, off);
  __shared__ float red[4];
  int wid = tid >> 6, lane = tid & 63;
  if (lane == 0) red[wid] = acc;
  __syncthreads();
  if (tid == 0) {
    float tot = red[0] + red[1] + red[2] + red[3];
    out[b] = 1.0f / (1.0f + __expf(-(tot + bo[0])));
  }
}

extern "C" void kernel_launch(void* const* d_in, const int* in_sizes, int n_in,
                              void* d_out, int out_size, void* d_ws, size_t ws_size,
                              hipStream_t stream)
{
  const int*   tokens  = (const int*)d_in[0];
  const int*   lengths = (const int*)d_in[1];
  const float* emb     = (const float*)d_in[2];
  const float* Wx_f    = (const float*)d_in[3];
  const float* Wh_f    = (const float*)d_in[4];
  const float* b_f     = (const float*)d_in[5];
  const float* Wx_b    = (const float*)d_in[6];
  const float* Wh_b    = (const float*)d_in[7];
  const float* b_b     = (const float*)d_in[8];
  const float* W1      = (const float*)d_in[9];
  const float* b1      = (const float*)d_in[10];
  const float* W2      = (const float*)d_in[11];
  const float* b2      = (const float*)d_in[12];
  const float* Wr      = (const float*)d_in[13];
  const float* Ur      = (const float*)d_in[14];
  const float* br      = (const float*)d_in[15];
  const float* Wc      = (const float*)d_in[16];
  const float* Uc      = (const float*)d_in[17];
  const float* bc      = (const float*)d_in[18];
  const float* q       = (const float*)d_in[19];
  const float* W_hops  = (const float*)d_in[20];
  const float* b_hops  = (const float*)d_in[21];
  const float* Wo      = (const float*)d_in[22];
  const float* bo      = (const float*)d_in[23];
  float* ws = (float*)d_ws;

  float* x      = ws;                          // BT*E   (later: part0)
  float* xp_f   = x + (size_t)BT * E;          // BT*G4  (later: xr | xc)
  float* xp_b   = xp_f + (size_t)BT * G4;      // BT*G4  (later: za | zb)
  float* facts  = xp_b + (size_t)BT * G4;      // BT*D
  float* att_h  = facts + (size_t)BT * D;      // BT*E
  float* scores = att_h + (size_t)BT * E;      // BT
  float* att    = scores + BT;                 // BT
  float* m0     = att + BT;                    // B*D
  float* m1     = m0 + (size_t)B * D;          // B*D
  float* epb    = m1 + (size_t)B * D;          // B*D
  float* Hbuf   = epb + (size_t)B * D;         // 2*B*D
  int*   syncA  = (int*)(Hbuf + (size_t)2 * B * D);  // 3*128 ints
  float* xr     = xp_f;                        // BT*D
  float* xc     = xp_f + (size_t)BT * D;       // BT*D
  float* za     = xp_b;                        // BT*D
  float* zb     = xp_b + (size_t)BT * D;       // BT*D
  float* part0  = x;                           // BT*E

  // 0) zero barrier counters (fresh every launch -> deterministic)
  k_zero<<<1, 512, 0, stream>>>(syncA, 3 * 128);
  // 1) embed + input projections
  k_gather<<<BT, 256, 0, stream>>>(tokens, emb, x);
  k_gemm<<<dim3(16, 121), 256, 0, stream>>>(x, Wx_f, b_f, nullptr, xp_f, BT, G4, E);
  k_gemm<<<dim3(16, 121), 256, 0, stream>>>(x, Wx_b, b_b, nullptr, xp_b, BT, G4, E);
  // 2) BiLSTM
  k_lstm<<<dim3(B, 2), 256, 0, stream>>>(xp_f, xp_b, Wh_f, Wh_b, lengths, facts);
  // 3) hop-invariant precomputes
  k_gemm<<<dim3(8, 121), 256, 0, stream>>>(facts, Wr, nullptr, nullptr, xr, BT, D, D);
  k_gemm<<<dim3(8, 121), 256, 0, stream>>>(facts, Wc, nullptr, nullptr, xc, BT, D, D);
  k_buildz<<<BT, 512, 0, stream>>>(facts, q, za, zb);
  k_gemm<<<dim3(5, 121), 256, 0, stream>>>(za, W1, b1, nullptr, part0, BT, E, D);
  k_gemm<<<dim3(5, 121), 256, 0, stream>>>(zb, W1 + (size_t)1024 * E, nullptr, part0, part0, BT, E, D);

  // 4) hops
  const float* m_in = q;
  float* mb[2] = {m0, m1};
  for (int i = 0; i < NH; ++i) {
    k_buildz<<<BT, 512, 0, stream>>>(facts, m_in, za, zb);
    k_gemm<<<dim3(5, 121), 256, 0, stream>>>(za, W1 + (size_t)512 * E, nullptr, part0, att_h, BT, E, D);
    k_gemm<<<dim3(5, 121), 256, 0, stream>>>(zb, W1 + (size_t)1536 * E, nullptr, att_h, att_h, BT, E, D);
    k_score<<<BT, 64, 0, stream>>>(att_h, W2, b2, scores);
    k_softmax<<<B, 128, 0, stream>>>(scores, lengths, att);
    k_gru_persist<<<B, 512, 0, stream>>>(xr, xc, Ur, Uc, br, bc, att, Hbuf,
                                         syncA + i * 128, epb);
    k_hop<<<B, 512, 0, stream>>>(m_in, epb, q,
                                 W_hops + (size_t)i * 3 * D * D, b_hops + (size_t)i * D,
                                 mb[i & 1]);
    m_in = mb[i & 1];
  }
  // 5) output
  k_out<<<B, 256, 0, stream>>>(m_in, q, Wo, bo, (float*)d_out);
}

// Round 3
// 6690.679 us; speedup vs baseline: 2.2911x; 2.2911x over previous
//
#include <hip/hip_runtime.h>

constexpr int B  = 64;
constexpr int T  = 121;
constexpr int E  = 300;
constexpr int H  = 256;
constexpr int G4 = 1024;   // 4*H
constexpr int D  = 512;    // 2*H
constexpr int NH = 3;
constexpr int BT = B * T;  // 7744

__device__ __forceinline__ float sigmoidf(float x) { return 1.0f / (1.0f + __expf(-x)); }
__device__ __forceinline__ float tanhf_fast(float x) {
  float e = __expf(2.0f * x);
  return 1.0f - 2.0f / (e + 1.0f);
}
__device__ __forceinline__ unsigned bf16rne(float x) {
  unsigned u = __float_as_uint(x);
  return (u + 0x7fffu + ((u >> 16) & 1u)) >> 16;
}
__device__ __forceinline__ float bf_lo(unsigned u) { return __uint_as_float(u << 16); }
__device__ __forceinline__ float bf_hi(unsigned u) { return __uint_as_float(u & 0xffff0000u); }

// ---------------- weight packing (runs once per launch, ~20us total) ----------------
// GRU: UP[i] = bf16(Ur[i]) | bf16(Uc[i])<<16   (elementwise, both [D][D] row-major)
__global__ void k_pack_gru(const float* __restrict__ Ur, const float* __restrict__ Uc,
                           unsigned* __restrict__ UP) {
  int i = blockIdx.x * 256 + threadIdx.x;
  UP[i] = bf16rne(Ur[i]) | (bf16rne(Uc[i]) << 16);
}
// LSTM: PA[k*256+j] = pack(Wh[k][j], Wh[k][j+256]); PB: gates g,o.
__global__ void k_pack_lstm(const float* __restrict__ Wh,
                            unsigned* __restrict__ PA, unsigned* __restrict__ PB) {
  int i = blockIdx.x * 256 + threadIdx.x;   // over 256*256
  int k = i >> 8, j = i & 255;
  const float* row = Wh + (size_t)k * G4;
  PA[i] = bf16rne(row[j])       | (bf16rne(row[j + 256]) << 16);
  PB[i] = bf16rne(row[j + 512]) | (bf16rne(row[j + 768]) << 16);
}

// ---------------- embedding gather ----------------
__global__ void k_gather(const int* __restrict__ tokens, const float* __restrict__ emb,
                         float* __restrict__ x) {
  int bt = blockIdx.x;
  int tok = tokens[bt];
  const float* src = emb + (size_t)tok * E;
  float* dst = x + (size_t)bt * E;
  for (int e = threadIdx.x; e < E; e += blockDim.x) dst[e] = src[e];
}

// ---------------- generic fp32 GEMM: C = A@W (+bias) (+Cin) ----------------
__global__ __launch_bounds__(256) void k_gemm(
    const float* __restrict__ A, const float* __restrict__ W,
    const float* __restrict__ bias, const float* __restrict__ Cin,
    float* __restrict__ C, int M, int N, int K)
{
  __shared__ float As[16][68];
  __shared__ float Ws[16][68];
  int tid = threadIdx.x;
  int tx = tid & 15, ty = tid >> 4;
  int row0 = blockIdx.y * 64, col0 = blockIdx.x * 64;
  float acc[4][4] = {};
  for (int k0 = 0; k0 < K; k0 += 16) {
#pragma unroll
    for (int i = 0; i < 4; ++i) {
      int idx = tid + i * 256;
      int kk = idx & 15, r = idx >> 4;
      int gk = k0 + kk;
      As[kk][r] = (gk < K) ? A[(size_t)(row0 + r) * K + gk] : 0.0f;
    }
#pragma unroll
    for (int i = 0; i < 4; ++i) {
      int idx = tid + i * 256;
      int c = idx & 63, kk = idx >> 6;
      int gk = k0 + kk, gc = col0 + c;
      Ws[kk][c] = (gk < K && gc < N) ? W[(size_t)gk * N + gc] : 0.0f;
    }
    __syncthreads();
#pragma unroll
    for (int k = 0; k < 16; ++k) {
      float4 av = *reinterpret_cast<const float4*>(&As[k][ty * 4]);
      float4 wv = *reinterpret_cast<const float4*>(&Ws[k][tx * 4]);
      float a4[4] = {av.x, av.y, av.z, av.w};
      float w4[4] = {wv.x, wv.y, wv.z, wv.w};
#pragma unroll
      for (int i = 0; i < 4; ++i)
#pragma unroll
        for (int j = 0; j < 4; ++j)
          acc[i][j] = fmaf(a4[i], w4[j], acc[i][j]);
    }
    __syncthreads();
  }
#pragma unroll
  for (int i = 0; i < 4; ++i) {
    int gr = row0 + ty * 4 + i;
#pragma unroll
    for (int j = 0; j < 4; ++j) {
      int gc = col0 + tx * 4 + j;
      if (gc < N) {
        float v = acc[i][j];
        if (bias) v += bias[gc];
        if (Cin)  v += Cin[(size_t)gr * N + gc];
        C[(size_t)gr * N + gc] = v;
      }
    }
  }
}

// ---------------- BiLSTM scan, bf16-packed Wh: 512KB/step/block from L2 ----------------
__global__ __launch_bounds__(256) void k_lstm(
    const float* __restrict__ xp_f, const float* __restrict__ xp_b,
    const unsigned* __restrict__ PA_f, const unsigned* __restrict__ PB_f,
    const unsigned* __restrict__ PA_b, const unsigned* __restrict__ PB_b,
    const int* __restrict__ lengths, float* __restrict__ facts)
{
  int b = blockIdx.x;
  int dir = blockIdx.y;
  const float* xp = dir ? xp_b : xp_f;
  const unsigned* PA = dir ? PA_b : PA_f;
  const unsigned* PB = dir ? PB_b : PB_f;
  int j = threadIdx.x;
  __shared__ float hs[H];
  hs[j] = 0.0f;
  float c = 0.0f, h = 0.0f;
  int nsteps = dir ? T : lengths[b];
  __syncthreads();
  for (int s = 0; s < nsteps; ++s) {
    int t = dir ? (T - 1 - s) : s;
    const float* xrow = xp + (size_t)(b * T + t) * G4;
    float g0 = xrow[j], g1 = xrow[j + 256], g2 = xrow[j + 512], g3 = xrow[j + 768];
#pragma unroll 4
    for (int k = 0; k < H; ++k) {
      float hv = hs[k];
      unsigned ua = PA[k * 256 + j];
      unsigned ub = PB[k * 256 + j];
      g0 = fmaf(hv, bf_lo(ua), g0);
      g1 = fmaf(hv, bf_hi(ua), g1);
      g2 = fmaf(hv, bf_lo(ub), g2);
      g3 = fmaf(hv, bf_hi(ub), g3);
    }
    float ig = sigmoidf(g0);
    float fg = sigmoidf(g1);
    float gg = tanhf_fast(g2);
    float og = sigmoidf(g3);
    c = fg * c + ig * gg;
    h = og * tanhf_fast(c);
    __syncthreads();
    hs[j] = h;
    facts[(size_t)(b * T + t) * D + dir * H + j] = h;
    __syncthreads();
  }
}

// ---------------- z halves ----------------
__global__ void k_buildz(const float* __restrict__ facts, const float* __restrict__ v,
                         float* __restrict__ za, float* __restrict__ zb) {
  int bt = blockIdx.x;
  int b = bt / T;
  const float* F = facts + (size_t)bt * D;
  const float* vb = v + (size_t)b * D;
  for (int d = threadIdx.x; d < D; d += blockDim.x) {
    float f = F[d], vv = vb[d];
    za[(size_t)bt * D + d] = f * vv;
    zb[(size_t)bt * D + d] = fabsf(f - vv);
  }
}

// ---------------- score ----------------
__global__ void k_score(const float* __restrict__ att_h, const float* __restrict__ W2,
                        const float* __restrict__ b2, float* __restrict__ s) {
  int bt = blockIdx.x;
  int tid = threadIdx.x;  // 64
  float acc = 0.f;
  for (int e = tid; e < E; e += 64)
    acc += tanhf_fast(att_h[(size_t)bt * E + e]) * W2[e];
  for (int off = 32; off > 0; off >>= 1) acc += __shfl_down(acc, off);
  if (tid == 0) s[bt] = acc + b2[0];
}

// ---------------- masked softmax ----------------
__global__ void k_softmax(const float* __restrict__ s, const int* __restrict__ lengths,
                          float* __restrict__ a) {
  int b = blockIdx.x;
  int t = threadIdx.x;  // 128
  int len = lengths[b];
  __shared__ float wred[2];
  float val = -1e30f;
  if (t < T) val = (t < len) ? s[b * T + t] : -1e9f;
  float mx = val;
  for (int off = 32; off > 0; off >>= 1) mx = fmaxf(mx, __shfl_xor(mx, off));
  int wid = t >> 6, lane = t & 63;
  if (lane == 0) wred[wid] = mx;
  __syncthreads();
  mx = fmaxf(wred[0], wred[1]);
  __syncthreads();
  float e = (t < T && t < len) ? __expf(val - mx) : 0.0f;
  float sum = e;
  for (int off = 32; off > 0; off >>= 1) sum += __shfl_xor(sum, off);
  if (lane == 0) wred[wid] = sum;
  __syncthreads();
  float tot = wred[0] + wred[1];
  if (t < T) a[b * T + t] = e / tot;
}

// ---------------- attention GRU, bf16-packed U: 1MB/step/block from L2 ----------------
// one block per batch, 512 threads = columns; att==0 exactly for t>=len -> early exit.
__global__ __launch_bounds__(512) void k_gru(
    const float* __restrict__ xr, const float* __restrict__ xc,
    const unsigned* __restrict__ UP,
    const float* __restrict__ br, const float* __restrict__ bc,
    const float* __restrict__ att, const int* __restrict__ lengths,
    float* __restrict__ ep)
{
  int b = blockIdx.x;
  int j = threadIdx.x;
  __shared__ float hs[D];
  hs[j] = 0.0f;
  float hj = 0.0f;
  int len = lengths[b];
  float brj = br[j], bcj = bc[j];
  __syncthreads();
  for (int t = 0; t < len; ++t) {
    float r0 = 0.f, r1 = 0.f, c0 = 0.f, c1 = 0.f;
#pragma unroll 4
    for (int k = 0; k < D; k += 2) {
      float ha = hs[k], hb = hs[k + 1];
      unsigned ua = UP[(size_t)k * D + j];
      unsigned ub = UP[(size_t)(k + 1) * D + j];
      r0 = fmaf(ha, bf_lo(ua), r0);
      c0 = fmaf(ha, bf_hi(ua), c0);
      r1 = fmaf(hb, bf_lo(ub), r1);
      c1 = fmaf(hb, bf_hi(ub), c1);
    }
    float racc = r0 + r1, cacc = c0 + c1;
    size_t base = (size_t)(b * T + t) * D;
    float r  = sigmoidf(xr[base + j] + racc + brj);
    float hc = tanhf_fast(xc[base + j] + r * cacc + bcj);
    float g = att[b * T + t];
    hj = g * hc + (1.f - g) * hj;
    __syncthreads();
    hs[j] = hj;
    __syncthreads();
  }
  ep[(size_t)b * D + j] = hj;
}

// ---------------- hop projection ----------------
__global__ __launch_bounds__(512) void k_hop(
    const float* __restrict__ m_in, const float* __restrict__ ep,
    const float* __restrict__ q, const float* __restrict__ Whop,
    const float* __restrict__ bhop, float* __restrict__ m_out)
{
  int b = blockIdx.x, j = threadIdx.x;
  __shared__ float av[3 * D];
  av[j]         = m_in[(size_t)b * D + j];
  av[D + j]     = ep[(size_t)b * D + j];
  av[2 * D + j] = q[(size_t)b * D + j];
  __syncthreads();
  float acc = bhop[j];
#pragma unroll 4
  for (int k = 0; k < 3 * D; ++k)
    acc = fmaf(av[k], Whop[(size_t)k * D + j], acc);
  m_out[(size_t)b * D + j] = fmaxf(acc, 0.0f);
}

// ---------------- output ----------------
__global__ void k_out(const float* __restrict__ m, const float* __restrict__ q,
                      const float* __restrict__ Wo, const float* __restrict__ bo,
                      float* __restrict__ out)
{
  int b = blockIdx.x, tid = threadIdx.x;  // 256
  float acc = 0.f;
  for (int k = tid; k < D; k += 256)
    acc += m[(size_t)b * D + k] * Wo[k] + q[(size_t)b * D + k] * Wo[D + k];
  for (int off = 32; off > 0; off >>= 1) acc += __shfl_down(acc, off);
  __shared__ float red[4];
  int wid = tid >> 6, lane = tid & 63;
  if (lane == 0) red[wid] = acc;
  __syncthreads();
  if (tid == 0) {
    float tot = red[0] + red[1] + red[2] + red[3];
    out[b] = 1.0f / (1.0f + __expf(-(tot + bo[0])));
  }
}

extern "C" void kernel_launch(void* const* d_in, const int* in_sizes, int n_in,
                              void* d_out, int out_size, void* d_ws, size_t ws_size,
                              hipStream_t stream)
{
  const int*   tokens  = (const int*)d_in[0];
  const int*   lengths = (const int*)d_in[1];
  const float* emb     = (const float*)d_in[2];
  const float* Wx_f    = (const float*)d_in[3];
  const float* Wh_f    = (const float*)d_in[4];
  const float* b_f     = (const float*)d_in[5];
  const float* Wx_b    = (const float*)d_in[6];
  const float* Wh_b    = (const float*)d_in[7];
  const float* b_b     = (const float*)d_in[8];
  const float* W1      = (const float*)d_in[9];
  const float* b1      = (const float*)d_in[10];
  const float* W2      = (const float*)d_in[11];
  const float* b2      = (const float*)d_in[12];
  const float* Wr      = (const float*)d_in[13];
  const float* Ur      = (const float*)d_in[14];
  const float* br      = (const float*)d_in[15];
  const float* Wc      = (const float*)d_in[16];
  const float* Uc      = (const float*)d_in[17];
  const float* bc      = (const float*)d_in[18];
  const float* q       = (const float*)d_in[19];
  const float* W_hops  = (const float*)d_in[20];
  const float* b_hops  = (const float*)d_in[21];
  const float* Wo      = (const float*)d_in[22];
  const float* bo      = (const float*)d_in[23];
  float* ws = (float*)d_ws;

  float* x      = ws;                          // BT*E   (later: part0)
  float* xp_f   = x + (size_t)BT * E;          // BT*G4  (later: xr | xc)
  float* xp_b   = xp_f + (size_t)BT * G4;      // BT*G4  (later: za | zb)
  float* facts  = xp_b + (size_t)BT * G4;      // BT*D
  float* att_h  = facts + (size_t)BT * D;      // BT*E
  float* scores = att_h + (size_t)BT * E;      // BT
  float* att    = scores + BT;                 // BT
  float* m0     = att + BT;                    // B*D
  float* m1     = m0 + (size_t)B * D;          // B*D
  float* epb    = m1 + (size_t)B * D;          // B*D
  unsigned* UP   = (unsigned*)(epb + (size_t)B * D);  // D*D uints
  unsigned* PA_f = UP + (size_t)D * D;         // 256*256 each
  unsigned* PB_f = PA_f + 256 * 256;
  unsigned* PA_b = PB_f + 256 * 256;
  unsigned* PB_b = PA_b + 256 * 256;
  float* xr     = xp_f;                        // BT*D
  float* xc     = xp_f + (size_t)BT * D;       // BT*D
  float* za     = xp_b;                        // BT*D
  float* zb     = xp_b + (size_t)BT * D;       // BT*D
  float* part0  = x;                           // BT*E

  // 0) pack recurrent weights to bf16
  k_pack_gru<<<D * D / 256, 256, 0, stream>>>(Ur, Uc, UP);
  k_pack_lstm<<<256, 256, 0, stream>>>(Wh_f, PA_f, PB_f);
  k_pack_lstm<<<256, 256, 0, stream>>>(Wh_b, PA_b, PB_b);
  // 1) embed + input projections
  k_gather<<<BT, 256, 0, stream>>>(tokens, emb, x);
  k_gemm<<<dim3(16, 121), 256, 0, stream>>>(x, Wx_f, b_f, nullptr, xp_f, BT, G4, E);
  k_gemm<<<dim3(16, 121), 256, 0, stream>>>(x, Wx_b, b_b, nullptr, xp_b, BT, G4, E);
  // 2) BiLSTM
  k_lstm<<<dim3(B, 2), 256, 0, stream>>>(xp_f, xp_b, PA_f, PB_f, PA_b, PB_b, lengths, facts);
  // 3) hop-invariant precomputes
  k_gemm<<<dim3(8, 121), 256, 0, stream>>>(facts, Wr, nullptr, nullptr, xr, BT, D, D);
  k_gemm<<<dim3(8, 121), 256, 0, stream>>>(facts, Wc, nullptr, nullptr, xc, BT, D, D);
  k_buildz<<<BT, 512, 0, stream>>>(facts, q, za, zb);
  k_gemm<<<dim3(5, 121), 256, 0, stream>>>(za, W1, b1, nullptr, part0, BT, E, D);
  k_gemm<<<dim3(5, 121), 256, 0, stream>>>(zb, W1 + (size_t)1024 * E, nullptr, part0, part0, BT, E, D);

  // 4) hops
  const float* m_in = q;
  float* mb[2] = {m0, m1};
  for (int i = 0; i < NH; ++i) {
    k_buildz<<<BT, 512, 0, stream>>>(facts, m_in, za, zb);
    k_gemm<<<dim3(5, 121), 256, 0, stream>>>(za, W1 + (size_t)512 * E, nullptr, part0, att_h, BT, E, D);
    k_gemm<<<dim3(5, 121), 256, 0, stream>>>(zb, W1 + (size_t)1536 * E, nullptr, att_h, att_h, BT, E, D);
    k_score<<<BT, 64, 0, stream>>>(att_h, W2, b2, scores);
    k_softmax<<<B, 128, 0, stream>>>(scores, lengths, att);
    k_gru<<<B, 512, 0, stream>>>(xr, xc, UP, br, bc, att, lengths, epb);
    k_hop<<<B, 512, 0, stream>>>(m_in, epb, q,
                                 W_hops + (size_t)i * 3 * D * D, b_hops + (size_t)i * D,
                                 mb[i & 1]);
    m_in = mb[i & 1];
  }
  // 5) output
  k_out<<<B, 256, 0, stream>>>(m_in, q, Wo, bo, (float*)d_out);
}

// Round 4
// 5195.741 us; speedup vs baseline: 2.9503x; 1.2877x over previous
//
#include <hip/hip_runtime.h>

constexpr int B  = 64;
constexpr int T  = 121;
constexpr int E  = 300;
constexpr int H  = 256;
constexpr int G4 = 1024;   // 4*H
constexpr int D  = 512;    // 2*H
constexpr int NH = 3;
constexpr int BT = B * T;  // 7744

__device__ __forceinline__ float sigmoidf(float x) { return 1.0f / (1.0f + __expf(-x)); }
__device__ __forceinline__ float tanhf_fast(float x) {
  float e = __expf(2.0f * x);
  return 1.0f - 2.0f / (e + 1.0f);
}
__device__ __forceinline__ unsigned bf16rne(float x) {
  unsigned u = __float_as_uint(x);
  return (u + 0x7fffu + ((u >> 16) & 1u)) >> 16;
}
__device__ __forceinline__ float bf_lo(unsigned u) { return __uint_as_float(u << 16); }
__device__ __forceinline__ float bf_hi(unsigned u) { return __uint_as_float(u & 0xffff0000u); }

// ---------------- weight packing ----------------
// GRU: UPQ[k4*D + j] = uint4 over k=4k4..4k4+3 of (bf16(Ur[k][j]) | bf16(Uc[k][j])<<16)
__global__ void k_pack_gru(const float* __restrict__ Ur, const float* __restrict__ Uc,
                           uint4* __restrict__ UPQ) {
  int idx = blockIdx.x * 256 + threadIdx.x;   // over (D/4)*D = 65536
  int k4 = idx >> 9, j = idx & 511;
  int k = 4 * k4;
  uint4 o;
  o.x = bf16rne(Ur[(size_t)(k + 0) * D + j]) | (bf16rne(Uc[(size_t)(k + 0) * D + j]) << 16);
  o.y = bf16rne(Ur[(size_t)(k + 1) * D + j]) | (bf16rne(Uc[(size_t)(k + 1) * D + j]) << 16);
  o.z = bf16rne(Ur[(size_t)(k + 2) * D + j]) | (bf16rne(Uc[(size_t)(k + 2) * D + j]) << 16);
  o.w = bf16rne(Ur[(size_t)(k + 3) * D + j]) | (bf16rne(Uc[(size_t)(k + 3) * D + j]) << 16);
  UPQ[idx] = o;
}
// LSTM: PAQ[k4*256+j] = uint4 over 4 k's of (bf16(Wh[k][j]) | bf16(Wh[k][j+256])<<16)
//       PBQ same for gates (g,o) = cols j+512, j+768
__global__ void k_pack_lstm(const float* __restrict__ Wh,
                            uint4* __restrict__ PAQ, uint4* __restrict__ PBQ) {
  int idx = blockIdx.x * 256 + threadIdx.x;   // over (H/4)*256 = 16384
  int k4 = idx >> 8, j = idx & 255;
  int k = 4 * k4;
  uint4 a, bq;
  const float* r0 = Wh + (size_t)(k + 0) * G4;
  const float* r1 = Wh + (size_t)(k + 1) * G4;
  const float* r2 = Wh + (size_t)(k + 2) * G4;
  const float* r3 = Wh + (size_t)(k + 3) * G4;
  a.x  = bf16rne(r0[j]) | (bf16rne(r0[j + 256]) << 16);
  a.y  = bf16rne(r1[j]) | (bf16rne(r1[j + 256]) << 16);
  a.z  = bf16rne(r2[j]) | (bf16rne(r2[j + 256]) << 16);
  a.w  = bf16rne(r3[j]) | (bf16rne(r3[j + 256]) << 16);
  bq.x = bf16rne(r0[j + 512]) | (bf16rne(r0[j + 768]) << 16);
  bq.y = bf16rne(r1[j + 512]) | (bf16rne(r1[j + 768]) << 16);
  bq.z = bf16rne(r2[j + 512]) | (bf16rne(r2[j + 768]) << 16);
  bq.w = bf16rne(r3[j + 512]) | (bf16rne(r3[j + 768]) << 16);
  PAQ[idx] = a;
  PBQ[idx] = bq;
}

// ---------------- embedding gather ----------------
__global__ void k_gather(const int* __restrict__ tokens, const float* __restrict__ emb,
                         float* __restrict__ x) {
  int bt = blockIdx.x;
  int tok = tokens[bt];
  const float* src = emb + (size_t)tok * E;
  float* dst = x + (size_t)bt * E;
  for (int e = threadIdx.x; e < E; e += blockDim.x) dst[e] = src[e];
}

// ---------------- generic fp32 GEMM: C = A@W (+bias) (+Cin) ----------------
__global__ __launch_bounds__(256) void k_gemm(
    const float* __restrict__ A, const float* __restrict__ W,
    const float* __restrict__ bias, const float* __restrict__ Cin,
    float* __restrict__ C, int M, int N, int K)
{
  __shared__ float As[16][68];
  __shared__ float Ws[16][68];
  int tid = threadIdx.x;
  int tx = tid & 15, ty = tid >> 4;
  int row0 = blockIdx.y * 64, col0 = blockIdx.x * 64;
  float acc[4][4] = {};
  for (int k0 = 0; k0 < K; k0 += 16) {
#pragma unroll
    for (int i = 0; i < 4; ++i) {
      int idx = tid + i * 256;
      int kk = idx & 15, r = idx >> 4;
      int gk = k0 + kk;
      As[kk][r] = (gk < K) ? A[(size_t)(row0 + r) * K + gk] : 0.0f;
    }
#pragma unroll
    for (int i = 0; i < 4; ++i) {
      int idx = tid + i * 256;
      int c = idx & 63, kk = idx >> 6;
      int gk = k0 + kk, gc = col0 + c;
      Ws[kk][c] = (gk < K && gc < N) ? W[(size_t)gk * N + gc] : 0.0f;
    }
    __syncthreads();
#pragma unroll
    for (int k = 0; k < 16; ++k) {
      float4 av = *reinterpret_cast<const float4*>(&As[k][ty * 4]);
      float4 wv = *reinterpret_cast<const float4*>(&Ws[k][tx * 4]);
      float a4[4] = {av.x, av.y, av.z, av.w};
      float w4[4] = {wv.x, wv.y, wv.z, wv.w};
#pragma unroll
      for (int i = 0; i < 4; ++i)
#pragma unroll
        for (int j = 0; j < 4; ++j)
          acc[i][j] = fmaf(a4[i], w4[j], acc[i][j]);
    }
    __syncthreads();
  }
#pragma unroll
  for (int i = 0; i < 4; ++i) {
    int gr = row0 + ty * 4 + i;
#pragma unroll
    for (int j = 0; j < 4; ++j) {
      int gc = col0 + tx * 4 + j;
      if (gc < N) {
        float v = acc[i][j];
        if (bias) v += bias[gc];
        if (Cin)  v += Cin[(size_t)gr * N + gc];
        C[(size_t)gr * N + gc] = v;
      }
    }
  }
}

// ---------------- BiLSTM scan: 512 threads, split-k halves, uint4 weight loads ------
__global__ __launch_bounds__(512) void k_lstm(
    const float* __restrict__ xp_f, const float* __restrict__ xp_b,
    const uint4* __restrict__ PAQ_f, const uint4* __restrict__ PBQ_f,
    const uint4* __restrict__ PAQ_b, const uint4* __restrict__ PBQ_b,
    const int* __restrict__ lengths, float* __restrict__ facts)
{
  int b = blockIdx.x;
  int dir = blockIdx.y;
  const float* xp = dir ? xp_b : xp_f;
  const uint4* PAQ = dir ? PAQ_b : PAQ_f;
  const uint4* PBQ = dir ? PBQ_b : PBQ_f;
  int tid = threadIdx.x;
  int j = tid & 255, half = tid >> 8;
  __shared__ float hs[H];
  __shared__ float4 red[512];
  hs[j] = 0.0f;
  float c = 0.0f, h = 0.0f;
  int nsteps = dir ? T : lengths[b];
  const uint4* pa = PAQ + (size_t)(half * 32) * 256 + j;
  const uint4* pb = PBQ + (size_t)(half * 32) * 256 + j;
  const float4* hs4 = reinterpret_cast<const float4*>(hs) + half * 32;
  __syncthreads();
  for (int s = 0; s < nsteps; ++s) {
    int t = dir ? (T - 1 - s) : s;
    float g0 = 0.f, g1 = 0.f, g2 = 0.f, g3 = 0.f;
#pragma unroll 4
    for (int k4 = 0; k4 < 32; ++k4) {
      uint4 a  = pa[(size_t)k4 * 256];
      uint4 bq = pb[(size_t)k4 * 256];
      float4 hv = hs4[k4];
      g0 = fmaf(hv.x, bf_lo(a.x), g0);  g1 = fmaf(hv.x, bf_hi(a.x), g1);
      g2 = fmaf(hv.x, bf_lo(bq.x), g2); g3 = fmaf(hv.x, bf_hi(bq.x), g3);
      g0 = fmaf(hv.y, bf_lo(a.y), g0);  g1 = fmaf(hv.y, bf_hi(a.y), g1);
      g2 = fmaf(hv.y, bf_lo(bq.y), g2); g3 = fmaf(hv.y, bf_hi(bq.y), g3);
      g0 = fmaf(hv.z, bf_lo(a.z), g0);  g1 = fmaf(hv.z, bf_hi(a.z), g1);
      g2 = fmaf(hv.z, bf_lo(bq.z), g2); g3 = fmaf(hv.z, bf_hi(bq.z), g3);
      g0 = fmaf(hv.w, bf_lo(a.w), g0);  g1 = fmaf(hv.w, bf_hi(a.w), g1);
      g2 = fmaf(hv.w, bf_lo(bq.w), g2); g3 = fmaf(hv.w, bf_hi(bq.w), g3);
    }
    red[tid] = make_float4(g0, g1, g2, g3);
    __syncthreads();
    if (half == 0) {
      float4 o = red[tid + 256];
      const float* xrow = xp + (size_t)(b * T + t) * G4;
      g0 += o.x + xrow[j];
      g1 += o.y + xrow[j + 256];
      g2 += o.z + xrow[j + 512];
      g3 += o.w + xrow[j + 768];
      float ig = sigmoidf(g0);
      float fg = sigmoidf(g1);
      float gg = tanhf_fast(g2);
      float og = sigmoidf(g3);
      c = fg * c + ig * gg;
      h = og * tanhf_fast(c);
      hs[j] = h;
      facts[(size_t)(b * T + t) * D + dir * H + j] = h;
    }
    __syncthreads();
  }
}

// ---------------- z halves ----------------
__global__ void k_buildz(const float* __restrict__ facts, const float* __restrict__ v,
                         float* __restrict__ za, float* __restrict__ zb) {
  int bt = blockIdx.x;
  int b = bt / T;
  const float* F = facts + (size_t)bt * D;
  const float* vb = v + (size_t)b * D;
  for (int d = threadIdx.x; d < D; d += blockDim.x) {
    float f = F[d], vv = vb[d];
    za[(size_t)bt * D + d] = f * vv;
    zb[(size_t)bt * D + d] = fabsf(f - vv);
  }
}

// ---------------- score ----------------
__global__ void k_score(const float* __restrict__ att_h, const float* __restrict__ W2,
                        const float* __restrict__ b2, float* __restrict__ s) {
  int bt = blockIdx.x;
  int tid = threadIdx.x;  // 64
  float acc = 0.f;
  for (int e = tid; e < E; e += 64)
    acc += tanhf_fast(att_h[(size_t)bt * E + e]) * W2[e];
  for (int off = 32; off > 0; off >>= 1) acc += __shfl_down(acc, off);
  if (tid == 0) s[bt] = acc + b2[0];
}

// ---------------- masked softmax ----------------
__global__ void k_softmax(const float* __restrict__ s, const int* __restrict__ lengths,
                          float* __restrict__ a) {
  int b = blockIdx.x;
  int t = threadIdx.x;  // 128
  int len = lengths[b];
  __shared__ float wred[2];
  float val = -1e30f;
  if (t < T) val = (t < len) ? s[b * T + t] : -1e9f;
  float mx = val;
  for (int off = 32; off > 0; off >>= 1) mx = fmaxf(mx, __shfl_xor(mx, off));
  int wid = t >> 6, lane = t & 63;
  if (lane == 0) wred[wid] = mx;
  __syncthreads();
  mx = fmaxf(wred[0], wred[1]);
  __syncthreads();
  float e = (t < T && t < len) ? __expf(val - mx) : 0.0f;
  float sum = e;
  for (int off = 32; off > 0; off >>= 1) sum += __shfl_xor(sum, off);
  if (lane == 0) wred[wid] = sum;
  __syncthreads();
  float tot = wred[0] + wred[1];
  if (t < T) a[b * T + t] = e / tot;
}

// ---------------- attention GRU: uint4 weight loads, float4 h reads ----------------
__global__ __launch_bounds__(512) void k_gru(
    const float* __restrict__ xr, const float* __restrict__ xc,
    const uint4* __restrict__ UPQ,
    const float* __restrict__ br, const float* __restrict__ bc,
    const float* __restrict__ att, const int* __restrict__ lengths,
    float* __restrict__ ep)
{
  int b = blockIdx.x;
  int j = threadIdx.x;
  __shared__ float hs[D];
  hs[j] = 0.0f;
  float hj = 0.0f;
  int len = lengths[b];
  float brj = br[j], bcj = bc[j];
  const uint4* up = UPQ + j;
  const float4* hs4 = reinterpret_cast<const float4*>(hs);
  __syncthreads();
  for (int t = 0; t < len; ++t) {
    float r0 = 0.f, r1 = 0.f, c0 = 0.f, c1 = 0.f;
#pragma unroll 4
    for (int k4 = 0; k4 < 128; ++k4) {
      uint4 u = up[(size_t)k4 * 512];
      float4 hv = hs4[k4];
      r0 = fmaf(hv.x, bf_lo(u.x), r0); c0 = fmaf(hv.x, bf_hi(u.x), c0);
      r1 = fmaf(hv.y, bf_lo(u.y), r1); c1 = fmaf(hv.y, bf_hi(u.y), c1);
      r0 = fmaf(hv.z, bf_lo(u.z), r0); c0 = fmaf(hv.z, bf_hi(u.z), c0);
      r1 = fmaf(hv.w, bf_lo(u.w), r1); c1 = fmaf(hv.w, bf_hi(u.w), c1);
    }
    float racc = r0 + r1, cacc = c0 + c1;
    size_t base = (size_t)(b * T + t) * D;
    float r  = sigmoidf(xr[base + j] + racc + brj);
    float hc = tanhf_fast(xc[base + j] + r * cacc + bcj);
    float g = att[b * T + t];
    hj = g * hc + (1.f - g) * hj;
    __syncthreads();
    hs[j] = hj;
    __syncthreads();
  }
  ep[(size_t)b * D + j] = hj;
}

// ---------------- hop projection ----------------
__global__ __launch_bounds__(512) void k_hop(
    const float* __restrict__ m_in, const float* __restrict__ ep,
    const float* __restrict__ q, const float* __restrict__ Whop,
    const float* __restrict__ bhop, float* __restrict__ m_out)
{
  int b = blockIdx.x, j = threadIdx.x;
  __shared__ float av[3 * D];
  av[j]         = m_in[(size_t)b * D + j];
  av[D + j]     = ep[(size_t)b * D + j];
  av[2 * D + j] = q[(size_t)b * D + j];
  __syncthreads();
  float acc = bhop[j];
#pragma unroll 4
  for (int k = 0; k < 3 * D; ++k)
    acc = fmaf(av[k], Whop[(size_t)k * D + j], acc);
  m_out[(size_t)b * D + j] = fmaxf(acc, 0.0f);
}

// ---------------- output ----------------
__global__ void k_out(const float* __restrict__ m, const float* __restrict__ q,
                      const float* __restrict__ Wo, const float* __restrict__ bo,
                      float* __restrict__ out)
{
  int b = blockIdx.x, tid = threadIdx.x;  // 256
  float acc = 0.f;
  for (int k = tid; k < D; k += 256)
    acc += m[(size_t)b * D + k] * Wo[k] + q[(size_t)b * D + k] * Wo[D + k];
  for (int off = 32; off > 0; off >>= 1) acc += __shfl_down(acc, off);
  __shared__ float red[4];
  int wid = tid >> 6, lane = tid & 63;
  if (lane == 0) red[wid] = acc;
  __syncthreads();
  if (tid == 0) {
    float tot = red[0] + red[1] + red[2] + red[3];
    out[b] = 1.0f / (1.0f + __expf(-(tot + bo[0])));
  }
}

extern "C" void kernel_launch(void* const* d_in, const int* in_sizes, int n_in,
                              void* d_out, int out_size, void* d_ws, size_t ws_size,
                              hipStream_t stream)
{
  const int*   tokens  = (const int*)d_in[0];
  const int*   lengths = (const int*)d_in[1];
  const float* emb     = (const float*)d_in[2];
  const float* Wx_f    = (const float*)d_in[3];
  const float* Wh_f    = (const float*)d_in[4];
  const float* b_f     = (const float*)d_in[5];
  const float* Wx_b    = (const float*)d_in[6];
  const float* Wh_b    = (const float*)d_in[7];
  const float* b_b     = (const float*)d_in[8];
  const float* W1      = (const float*)d_in[9];
  const float* b1      = (const float*)d_in[10];
  const float* W2      = (const float*)d_in[11];
  const float* b2      = (const float*)d_in[12];
  const float* Wr      = (const float*)d_in[13];
  const float* Ur      = (const float*)d_in[14];
  const float* br      = (const float*)d_in[15];
  const float* Wc      = (const float*)d_in[16];
  const float* Uc      = (const float*)d_in[17];
  const float* bc      = (const float*)d_in[18];
  const float* q       = (const float*)d_in[19];
  const float* W_hops  = (const float*)d_in[20];
  const float* b_hops  = (const float*)d_in[21];
  const float* Wo      = (const float*)d_in[22];
  const float* bo      = (const float*)d_in[23];
  float* ws = (float*)d_ws;

  float* x      = ws;                          // BT*E   (later: part0)
  float* xp_f   = x + (size_t)BT * E;          // BT*G4  (later: xr | xc)
  float* xp_b   = xp_f + (size_t)BT * G4;      // BT*G4  (later: za | zb)
  float* facts  = xp_b + (size_t)BT * G4;      // BT*D
  float* att_h  = facts + (size_t)BT * D;      // BT*E
  float* scores = att_h + (size_t)BT * E;      // BT
  float* att    = scores + BT;                 // BT
  float* m0     = att + BT;                    // B*D
  float* m1     = m0 + (size_t)B * D;          // B*D
  float* epb    = m1 + (size_t)B * D;          // B*D
  uint4* UPQ    = (uint4*)(epb + (size_t)B * D);     // (D/4)*D uint4 = 1MB
  uint4* PAQ_f  = UPQ + (size_t)(D / 4) * D;         // (H/4)*256 uint4 = 256KB each
  uint4* PBQ_f  = PAQ_f + (H / 4) * 256;
  uint4* PAQ_b  = PBQ_f + (H / 4) * 256;
  uint4* PBQ_b  = PAQ_b + (H / 4) * 256;
  float* xr     = xp_f;                        // BT*D
  float* xc     = xp_f + (size_t)BT * D;       // BT*D
  float* za     = xp_b;                        // BT*D
  float* zb     = xp_b + (size_t)BT * D;       // BT*D
  float* part0  = x;                           // BT*E

  // 0) pack recurrent weights to bf16 (uint4-grouped rows)
  k_pack_gru<<<(D / 4) * D / 256, 256, 0, stream>>>(Ur, Uc, UPQ);
  k_pack_lstm<<<(H / 4) * 256 / 256, 256, 0, stream>>>(Wh_f, PAQ_f, PBQ_f);
  k_pack_lstm<<<(H / 4) * 256 / 256, 256, 0, stream>>>(Wh_b, PAQ_b, PBQ_b);
  // 1) embed + input projections
  k_gather<<<BT, 256, 0, stream>>>(tokens, emb, x);
  k_gemm<<<dim3(16, 121), 256, 0, stream>>>(x, Wx_f, b_f, nullptr, xp_f, BT, G4, E);
  k_gemm<<<dim3(16, 121), 256, 0, stream>>>(x, Wx_b, b_b, nullptr, xp_b, BT, G4, E);
  // 2) BiLSTM
  k_lstm<<<dim3(B, 2), 512, 0, stream>>>(xp_f, xp_b, PAQ_f, PBQ_f, PAQ_b, PBQ_b, lengths, facts);
  // 3) hop-invariant precomputes
  k_gemm<<<dim3(8, 121), 256, 0, stream>>>(facts, Wr, nullptr, nullptr, xr, BT, D, D);
  k_gemm<<<dim3(8, 121), 256, 0, stream>>>(facts, Wc, nullptr, nullptr, xc, BT, D, D);
  k_buildz<<<BT, 512, 0, stream>>>(facts, q, za, zb);
  k_gemm<<<dim3(5, 121), 256, 0, stream>>>(za, W1, b1, nullptr, part0, BT, E, D);
  k_gemm<<<dim3(5, 121), 256, 0, stream>>>(zb, W1 + (size_t)1024 * E, nullptr, part0, part0, BT, E, D);

  // 4) hops
  const float* m_in = q;
  float* mb[2] = {m0, m1};
  for (int i = 0; i < NH; ++i) {
    k_buildz<<<BT, 512, 0, stream>>>(facts, m_in, za, zb);
    k_gemm<<<dim3(5, 121), 256, 0, stream>>>(za, W1 + (size_t)512 * E, nullptr, part0, att_h, BT, E, D);
    k_gemm<<<dim3(5, 121), 256, 0, stream>>>(zb, W1 + (size_t)1536 * E, nullptr, att_h, att_h, BT, E, D);
    k_score<<<BT, 64, 0, stream>>>(att_h, W2, b2, scores);
    k_softmax<<<B, 128, 0, stream>>>(scores, lengths, att);
    k_gru<<<B, 512, 0, stream>>>(xr, xc, UPQ, br, bc, att, lengths, epb);
    k_hop<<<B, 512, 0, stream>>>(m_in, epb, q,
                                 W_hops + (size_t)i * 3 * D * D, b_hops + (size_t)i * D,
                                 mb[i & 1]);
    m_in = mb[i & 1];
  }
  // 5) output
  k_out<<<B, 256, 0, stream>>>(m_in, q, Wo, bo, (float*)d_out);
}

// Round 6
// 4469.537 us; speedup vs baseline: 3.4297x; 1.1625x over previous
//
#include <hip/hip_runtime.h>

constexpr int B  = 64;
constexpr int T  = 121;
constexpr int E  = 300;
constexpr int Ep = 320;    // E padded to K-chunk multiple
constexpr int H  = 256;
constexpr int G4 = 1024;   // 4*H
constexpr int D  = 512;    // 2*H
constexpr int NH = 3;
constexpr int BT = B * T;  // 7744
constexpr int Mp = 7808;   // 61*128, M padded for 128-row tiles

using short8 = __attribute__((ext_vector_type(8))) short;
using f32x4  = __attribute__((ext_vector_type(4))) float;

__device__ __forceinline__ float sigmoidf(float x) { return 1.0f / (1.0f + __expf(-x)); }
__device__ __forceinline__ float tanhf_fast(float x) {
  float e = __expf(2.0f * x);
  return 1.0f - 2.0f / (e + 1.0f);
}
__device__ __forceinline__ unsigned bf16rne(float x) {
  unsigned u = __float_as_uint(x);
  return (u + 0x7fffu + ((u >> 16) & 1u)) >> 16;
}
__device__ __forceinline__ float bf_lo(unsigned u) { return __uint_as_float(u << 16); }
__device__ __forceinline__ float bf_hi(unsigned u) { return __uint_as_float(u & 0xffff0000u); }
__device__ __forceinline__ float bfu(unsigned short u) { return __uint_as_float(((unsigned)u) << 16); }

// ---------------- weight packing ----------------
// GRU: UPQ[k4*D + j] = uint4 over k=4k4..4k4+3 of (bf16(Ur)|bf16(Uc)<<16)  [round-4 verified]
__global__ void k_pack_gru(const float* __restrict__ Ur, const float* __restrict__ Uc,
                           uint4* __restrict__ UPQ) {
  int idx = blockIdx.x * 256 + threadIdx.x;   // over (D/4)*D = 65536
  int k4 = idx >> 9, j = idx & 511;
  int k = 4 * k4;
  uint4 o;
  o.x = bf16rne(Ur[(size_t)(k + 0) * D + j]) | (bf16rne(Uc[(size_t)(k + 0) * D + j]) << 16);
  o.y = bf16rne(Ur[(size_t)(k + 1) * D + j]) | (bf16rne(Uc[(size_t)(k + 1) * D + j]) << 16);
  o.z = bf16rne(Ur[(size_t)(k + 2) * D + j]) | (bf16rne(Uc[(size_t)(k + 2) * D + j]) << 16);
  o.w = bf16rne(Ur[(size_t)(k + 3) * D + j]) | (bf16rne(Uc[(size_t)(k + 3) * D + j]) << 16);
  UPQ[idx] = o;
}

// LSTM: bf16 pair-packed, uint4-grouped (round-4 verified)
__global__ void k_pack_lstm(const float* __restrict__ Wh,
                            uint4* __restrict__ PAQ, uint4* __restrict__ PBQ) {
  int idx = blockIdx.x * 256 + threadIdx.x;   // over (H/4)*256 = 16384
  int k4 = idx >> 8, j = idx & 255;
  int k = 4 * k4;
  uint4 a, bq;
  const float* r0 = Wh + (size_t)(k + 0) * G4;
  const float* r1 = Wh + (size_t)(k + 1) * G4;
  const float* r2 = Wh + (size_t)(k + 2) * G4;
  const float* r3 = Wh + (size_t)(k + 3) * G4;
  a.x  = bf16rne(r0[j]) | (bf16rne(r0[j + 256]) << 16);
  a.y  = bf16rne(r1[j]) | (bf16rne(r1[j + 256]) << 16);
  a.z  = bf16rne(r2[j]) | (bf16rne(r2[j + 256]) << 16);
  a.w  = bf16rne(r3[j]) | (bf16rne(r3[j + 256]) << 16);
  bq.x = bf16rne(r0[j + 512]) | (bf16rne(r0[j + 768]) << 16);
  bq.y = bf16rne(r1[j + 512]) | (bf16rne(r1[j + 768]) << 16);
  bq.z = bf16rne(r2[j + 512]) | (bf16rne(r2[j + 768]) << 16);
  bq.w = bf16rne(r3[j + 512]) | (bf16rne(r3[j + 768]) << 16);
  PAQ[idx] = a;
  PBQ[idx] = bq;
}

// generic B^T bf16 pack with zero padding: WT[n*Kpad + k] = bf16(W[k*stride + n]) or 0
__global__ void k_packT(const float* __restrict__ W, unsigned short* __restrict__ WT,
                        int Ksrc, int Nsrc, int stride, int Kpad) {
  int idx = blockIdx.x * 256 + threadIdx.x;
  int n = idx / Kpad, k = idx - n * Kpad;
  float v = (k < Ksrc && n < Nsrc) ? W[(size_t)k * stride + n] : 0.0f;
  WT[idx] = (unsigned short)bf16rne(v);
}

// ---------------- embedding gather -> bf16, K-padded ----------------
__global__ void k_gather(const int* __restrict__ tokens, const float* __restrict__ emb,
                         unsigned short* __restrict__ xh) {
  int bt = blockIdx.x;
  int tok = tokens[bt];
  const float* src = emb + (size_t)tok * E;
  unsigned short* dst = xh + (size_t)bt * Ep;
  for (int e = threadIdx.x; e < Ep; e += 256)
    dst[e] = (e < E) ? (unsigned short)bf16rne(src[e]) : (unsigned short)0;
}

// ---------------- bf16 MFMA GEMM: C = A1@B1t^T [+ A2@B2t^T] (+bias) (+Cin) ----------
// A: [Mp][lda] bf16 row-major. Bt: [Npad][K] bf16 (= B^T). C fp32 [BT][Cstride].
// Tile 128x64, 4 waves, each wave 32 rows x 64 cols (2x4 16x16 frags), BK=32.
__global__ __launch_bounds__(256) void k_gemm_mfma(
    const unsigned short* __restrict__ A1, const unsigned short* __restrict__ B1, int K1, int lda1,
    const unsigned short* __restrict__ A2, const unsigned short* __restrict__ B2, int K2, int lda2,
    const float* __restrict__ bias, const float* __restrict__ Cin,
    float* __restrict__ C, int Nreal, int Cstride)
{
  __shared__ unsigned short As[128][40];   // 80B rows: 16B-aligned, 2-way bank alias (free)
  __shared__ unsigned short Bs[64][40];
  int tid = threadIdx.x;
  int l = tid & 63, w = tid >> 6;
  int row0 = blockIdx.y * 128, col0 = blockIdx.x * 64;
  int lrow = l & 15, lk = (l >> 4) * 8, lq = (l >> 4) * 4;
  int ar = tid >> 1, asg = (tid & 1) * 16;   // A: 2x16B per thread
  int br = tid >> 2, bsg = (tid & 3) * 8;    // B: 1x16B per thread
  f32x4 acc[2][4] = {};
#pragma unroll 1
  for (int pass = 0; pass < 2; ++pass) {
    const unsigned short* A  = pass ? A2 : A1;
    const unsigned short* Bt = pass ? B2 : B1;
    int K   = pass ? K2 : K1;
    int lda = pass ? lda2 : lda1;
    if (K == 0) break;
    for (int k0 = 0; k0 < K; k0 += 32) {
      const uint4* ga = (const uint4*)(A + (size_t)(row0 + ar) * lda + k0 + asg);
      uint4 a0 = ga[0], a1 = ga[1];
      uint4 b0 = *(const uint4*)(Bt + (size_t)(col0 + br) * K + k0 + bsg);
      __syncthreads();               // previous chunk's frag reads complete
      *(uint4*)&As[ar][asg]     = a0;
      *(uint4*)&As[ar][asg + 8] = a1;
      *(uint4*)&Bs[br][bsg]     = b0;
      __syncthreads();               // staging visible
      short8 av[2], bv[4];
#pragma unroll
      for (int f = 0; f < 2; ++f)
        av[f] = *(const short8*)&As[w * 32 + f * 16 + lrow][lk];
#pragma unroll
      for (int fc = 0; fc < 4; ++fc)
        bv[fc] = *(const short8*)&Bs[fc * 16 + lrow][lk];
#pragma unroll
      for (int f = 0; f < 2; ++f)
#pragma unroll
        for (int fc = 0; fc < 4; ++fc)
          acc[f][fc] = __builtin_amdgcn_mfma_f32_16x16x32_bf16(av[f], bv[fc], acc[f][fc], 0, 0, 0);
    }
  }
  // epilogue: m89-verified D map: col = lane&15, row = (lane>>4)*4 + reg
#pragma unroll
  for (int f = 0; f < 2; ++f) {
#pragma unroll
    for (int fc = 0; fc < 4; ++fc) {
      int c = col0 + fc * 16 + lrow;
      if (c < Nreal) {
        float bb = bias ? bias[c] : 0.0f;
#pragma unroll
        for (int i = 0; i < 4; ++i) {
          int r = row0 + w * 32 + f * 16 + lq + i;
          if (r < BT) {
            float v = acc[f][fc][i] + bb;
            if (Cin) v += Cin[(size_t)r * Cstride + c];
            C[(size_t)r * Cstride + c] = v;
          }
        }
      }
    }
  }
}

// ---------------- BiLSTM scan: 512 thr split-k, bf16 weights; writes bf16 facts ------
__global__ __launch_bounds__(512) void k_lstm(
    const float* __restrict__ xp_f, const float* __restrict__ xp_b,
    const uint4* __restrict__ PAQ_f, const uint4* __restrict__ PBQ_f,
    const uint4* __restrict__ PAQ_b, const uint4* __restrict__ PBQ_b,
    const int* __restrict__ lengths, unsigned short* __restrict__ factsh)
{
  int b = blockIdx.x;
  int dir = blockIdx.y;
  const float* xp = dir ? xp_b : xp_f;
  const uint4* PAQ = dir ? PAQ_b : PAQ_f;
  const uint4* PBQ = dir ? PBQ_b : PBQ_f;
  int tid = threadIdx.x;
  int j = tid & 255, half = tid >> 8;
  __shared__ float hs[H];
  __shared__ float4 red[512];
  hs[j] = 0.0f;
  float c = 0.0f, h = 0.0f;
  int nsteps = dir ? T : lengths[b];
  const uint4* pa = PAQ + (size_t)(half * 32) * 256 + j;
  const uint4* pb = PBQ + (size_t)(half * 32) * 256 + j;
  const float4* hs4 = reinterpret_cast<const float4*>(hs) + half * 32;
  __syncthreads();
  for (int s = 0; s < nsteps; ++s) {
    int t = dir ? (T - 1 - s) : s;
    float g0 = 0.f, g1 = 0.f, g2 = 0.f, g3 = 0.f;
#pragma unroll 4
    for (int k4 = 0; k4 < 32; ++k4) {
      uint4 a  = pa[(size_t)k4 * 256];
      uint4 bq = pb[(size_t)k4 * 256];
      float4 hv = hs4[k4];
      g0 = fmaf(hv.x, bf_lo(a.x), g0);  g1 = fmaf(hv.x, bf_hi(a.x), g1);
      g2 = fmaf(hv.x, bf_lo(bq.x), g2); g3 = fmaf(hv.x, bf_hi(bq.x), g3);
      g0 = fmaf(hv.y, bf_lo(a.y), g0);  g1 = fmaf(hv.y, bf_hi(a.y), g1);
      g2 = fmaf(hv.y, bf_lo(bq.y), g2); g3 = fmaf(hv.y, bf_hi(bq.y), g3);
      g0 = fmaf(hv.z, bf_lo(a.z), g0);  g1 = fmaf(hv.z, bf_hi(a.z), g1);
      g2 = fmaf(hv.z, bf_lo(bq.z), g2); g3 = fmaf(hv.z, bf_hi(bq.z), g3);
      g0 = fmaf(hv.w, bf_lo(a.w), g0);  g1 = fmaf(hv.w, bf_hi(a.w), g1);
      g2 = fmaf(hv.w, bf_lo(bq.w), g2); g3 = fmaf(hv.w, bf_hi(bq.w), g3);
    }
    red[tid] = make_float4(g0, g1, g2, g3);
    __syncthreads();
    if (half == 0) {
      float4 o = red[tid + 256];
      const float* xrow = xp + (size_t)(b * T + t) * G4;
      g0 += o.x + xrow[j];
      g1 += o.y + xrow[j + 256];
      g2 += o.z + xrow[j + 512];
      g3 += o.w + xrow[j + 768];
      float ig = sigmoidf(g0);
      float fg = sigmoidf(g1);
      float gg = tanhf_fast(g2);
      float og = sigmoidf(g3);
      c = fg * c + ig * gg;
      h = og * tanhf_fast(c);
      hs[j] = h;
      factsh[(size_t)(b * T + t) * D + dir * H + j] = (unsigned short)bf16rne(h);
    }
    __syncthreads();
  }
}

// ---------------- z halves -> bf16 ----------------
__global__ void k_buildz(const unsigned short* __restrict__ factsh, const float* __restrict__ v,
                         unsigned short* __restrict__ za, unsigned short* __restrict__ zb) {
  int bt = blockIdx.x;
  int b = bt / T;
  int d = threadIdx.x;  // 512
  float f = bfu(factsh[(size_t)bt * D + d]);
  float vv = v[(size_t)b * D + d];
  za[(size_t)bt * D + d] = (unsigned short)bf16rne(f * vv);
  zb[(size_t)bt * D + d] = (unsigned short)bf16rne(fabsf(f - vv));
}

// ---------------- score ----------------
__global__ void k_score(const float* __restrict__ att_h, const float* __restrict__ W2,
                        const float* __restrict__ b2, float* __restrict__ s) {
  int bt = blockIdx.x;
  int tid = threadIdx.x;  // 64
  float acc = 0.f;
  for (int e = tid; e < E; e += 64)
    acc += tanhf_fast(att_h[(size_t)bt * E + e]) * W2[e];
  for (int off = 32; off > 0; off >>= 1) acc += __shfl_down(acc, off);
  if (tid == 0) s[bt] = acc + b2[0];
}

// ---------------- masked softmax ----------------
__global__ void k_softmax(const float* __restrict__ s, const int* __restrict__ lengths,
                          float* __restrict__ a) {
  int b = blockIdx.x;
  int t = threadIdx.x;  // 128
  int len = lengths[b];
  __shared__ float wred[2];
  float val = -1e30f;
  if (t < T) val = (t < len) ? s[b * T + t] : -1e9f;
  float mx = val;
  for (int off = 32; off > 0; off >>= 1) mx = fmaxf(mx, __shfl_xor(mx, off));
  int wid = t >> 6, lane = t & 63;
  if (lane == 0) wred[wid] = mx;
  __syncthreads();
  mx = fmaxf(wred[0], wred[1]);
  __syncthreads();
  float e = (t < T && t < len) ? __expf(val - mx) : 0.0f;
  float sum = e;
  for (int off = 32; off > 0; off >>= 1) sum += __shfl_xor(sum, off);
  if (lane == 0) wred[wid] = sum;
  __syncthreads();
  float tot = wred[0] + wred[1];
  if (t < T) a[b * T + t] = e / tot;
}

// ---------------- attention GRU (round-4 verified): bf16 packed U, uint4 loads ------
__global__ __launch_bounds__(512) void k_gru(
    const float* __restrict__ xr, const float* __restrict__ xc,
    const uint4* __restrict__ UPQ,
    const float* __restrict__ br, const float* __restrict__ bc,
    const float* __restrict__ att, const int* __restrict__ lengths,
    float* __restrict__ ep)
{
  int b = blockIdx.x;
  int j = threadIdx.x;
  __shared__ float hs[D];
  hs[j] = 0.0f;
  float hj = 0.0f;
  int len = lengths[b];
  float brj = br[j], bcj = bc[j];
  const uint4* up = UPQ + j;
  const float4* hs4 = reinterpret_cast<const float4*>(hs);
  __syncthreads();
  for (int t = 0; t < len; ++t) {
    float r0 = 0.f, r1 = 0.f, c0 = 0.f, c1 = 0.f;
#pragma unroll 4
    for (int k4 = 0; k4 < 128; ++k4) {
      uint4 u = up[(size_t)k4 * 512];
      float4 hv = hs4[k4];
      r0 = fmaf(hv.x, bf_lo(u.x), r0); c0 = fmaf(hv.x, bf_hi(u.x), c0);
      r1 = fmaf(hv.y, bf_lo(u.y), r1); c1 = fmaf(hv.y, bf_hi(u.y), c1);
      r0 = fmaf(hv.z, bf_lo(u.z), r0); c0 = fmaf(hv.z, bf_hi(u.z), c0);
      r1 = fmaf(hv.w, bf_lo(u.w), r1); c1 = fmaf(hv.w, bf_hi(u.w), c1);
    }
    float racc = r0 + r1, cacc = c0 + c1;
    size_t base = (size_t)(b * T + t) * D;
    float r  = sigmoidf(xr[base + j] + racc + brj);
    float hc = tanhf_fast(xc[base + j] + r * cacc + bcj);
    float g = att[b * T + t];
    hj = g * hc + (1.f - g) * hj;
    __syncthreads();
    hs[j] = hj;
    __syncthreads();
  }
  ep[(size_t)b * D + j] = hj;
}

// ---------------- hop projection ----------------
__global__ __launch_bounds__(512) void k_hop(
    const float* __restrict__ m_in, const float* __restrict__ ep,
    const float* __restrict__ q, const float* __restrict__ Whop,
    const float* __restrict__ bhop, float* __restrict__ m_out)
{
  int b = blockIdx.x, j = threadIdx.x;
  __shared__ float av[3 * D];
  av[j]         = m_in[(size_t)b * D + j];
  av[D + j]     = ep[(size_t)b * D + j];
  av[2 * D + j] = q[(size_t)b * D + j];
  __syncthreads();
  float acc = bhop[j];
#pragma unroll 4
  for (int k = 0; k < 3 * D; ++k)
    acc = fmaf(av[k], Whop[(size_t)k * D + j], acc);
  m_out[(size_t)b * D + j] = fmaxf(acc, 0.0f);
}

// ---------------- output ----------------
__global__ void k_out(const float* __restrict__ m, const float* __restrict__ q,
                      const float* __restrict__ Wo, const float* __restrict__ bo,
                      float* __restrict__ out)
{
  int b = blockIdx.x, tid = threadIdx.x;  // 256
  float acc = 0.f;
  for (int k = tid; k < D; k += 256)
    acc += m[(size_t)b * D + k] * Wo[k] + q[(size_t)b * D + k] * Wo[D + k];
  for (int off = 32; off > 0; off >>= 1) acc += __shfl_down(acc, off);
  __shared__ float red[4];
  int wid = tid >> 6, lane = tid & 63;
  if (lane == 0) red[wid] = acc;
  __syncthreads();
  if (tid == 0) {
    float tot = red[0] + red[1] + red[2] + red[3];
    out[b] = 1.0f / (1.0f + __expf(-(tot + bo[0])));
  }
}

extern "C" void kernel_launch(void* const* d_in, const int* in_sizes, int n_in,
                              void* d_out, int out_size, void* d_ws, size_t ws_size,
                              hipStream_t stream)
{
  const int*   tokens  = (const int*)d_in[0];
  const int*   lengths = (const int*)d_in[1];
  const float* emb     = (const float*)d_in[2];
  const float* Wx_f    = (const float*)d_in[3];
  const float* Wh_f    = (const float*)d_in[4];
  const float* b_f     = (const float*)d_in[5];
  const float* Wx_b    = (const float*)d_in[6];
  const float* Wh_b    = (const float*)d_in[7];
  const float* b_b     = (const float*)d_in[8];
  const float* W1      = (const float*)d_in[9];
  const float* b1      = (const float*)d_in[10];
  const float* W2      = (const float*)d_in[11];
  const float* b2      = (const float*)d_in[12];
  const float* Wr      = (const float*)d_in[13];
  const float* Ur      = (const float*)d_in[14];
  const float* br      = (const float*)d_in[15];
  const float* Wc      = (const float*)d_in[16];
  const float* Uc      = (const float*)d_in[17];
  const float* bc      = (const float*)d_in[18];
  const float* q       = (const float*)d_in[19];
  const float* W_hops  = (const float*)d_in[20];
  const float* b_hops  = (const float*)d_in[21];
  const float* Wo      = (const float*)d_in[22];
  const float* bo      = (const float*)d_in[23];
  float* ws = (float*)d_ws;

  // ---- workspace layout (float units; all sizes multiples of 4 => 16B alignment) ----
  float* p = ws;
  unsigned short* xh = (unsigned short*)p;  p += (size_t)Mp * Ep / 2;       // bf16 [Mp][320]
  float* xp_f   = p;  p += (size_t)BT * G4;                                 // later: xr | xc
  float* xp_b   = p;  p += (size_t)BT * G4;                                 // later: za | zb
  unsigned short* factsh = (unsigned short*)p;  p += (size_t)Mp * D / 2;    // bf16 [Mp][512]
  float* att_h  = p;  p += (size_t)BT * E;
  float* part0  = p;  p += (size_t)BT * E;
  float* scores = p;  p += BT;
  float* att    = p;  p += BT;
  float* m0     = p;  p += (size_t)B * D;
  float* m1     = p;  p += (size_t)B * D;
  float* epb    = p;  p += (size_t)B * D;
  uint4* UPQ    = (uint4*)p;  p += (size_t)(D / 4) * D * 4;                 // 1MB
  uint4* PAQ_f  = (uint4*)p;  p += (size_t)(H / 4) * 256 * 4;
  uint4* PBQ_f  = (uint4*)p;  p += (size_t)(H / 4) * 256 * 4;
  uint4* PAQ_b  = (uint4*)p;  p += (size_t)(H / 4) * 256 * 4;
  uint4* PBQ_b  = (uint4*)p;  p += (size_t)(H / 4) * 256 * 4;
  unsigned short* WxT_f = (unsigned short*)p;  p += (size_t)G4 * Ep / 2;    // [1024][320]
  unsigned short* WxT_b = (unsigned short*)p;  p += (size_t)G4 * Ep / 2;
  unsigned short* WrT   = (unsigned short*)p;  p += (size_t)D * D / 2;      // [512][512]
  unsigned short* WcT   = (unsigned short*)p;  p += (size_t)D * D / 2;
  unsigned short* W1T[4];
  for (int c = 0; c < 4; ++c) { W1T[c] = (unsigned short*)p; p += (size_t)Ep * D / 2; }  // [320][512]
  // aliases (after LSTM consumes xp_f/xp_b)
  float* xr = xp_f;                                   // fp32 [BT][512]
  float* xc = xp_f + (size_t)BT * D;
  unsigned short* za = (unsigned short*)xp_b;         // bf16 [Mp][512]
  unsigned short* zb = (unsigned short*)xp_b + (size_t)Mp * D;

  // 0) pack weights
  k_pack_gru<<<(D / 4) * D / 256, 256, 0, stream>>>(Ur, Uc, UPQ);
  k_pack_lstm<<<(H / 4) * 256 / 256, 256, 0, stream>>>(Wh_f, PAQ_f, PBQ_f);
  k_pack_lstm<<<(H / 4) * 256 / 256, 256, 0, stream>>>(Wh_b, PAQ_b, PBQ_b);
  k_packT<<<G4 * Ep / 256, 256, 0, stream>>>(Wx_f, WxT_f, E, G4, G4, Ep);
  k_packT<<<G4 * Ep / 256, 256, 0, stream>>>(Wx_b, WxT_b, E, G4, G4, Ep);
  k_packT<<<D * D / 256, 256, 0, stream>>>(Wr, WrT, D, D, D, D);
  k_packT<<<D * D / 256, 256, 0, stream>>>(Wc, WcT, D, D, D, D);
  for (int c = 0; c < 4; ++c)
    k_packT<<<Ep * D / 256, 256, 0, stream>>>(W1 + (size_t)c * D * E, W1T[c], D, E, E, D);

  // 1) embed (bf16, K-padded) + input projections (MFMA)
  k_gather<<<BT, 256, 0, stream>>>(tokens, emb, xh);
  k_gemm_mfma<<<dim3(G4 / 64, Mp / 128), 256, 0, stream>>>(
      xh, WxT_f, Ep, Ep, nullptr, nullptr, 0, 0, b_f, nullptr, xp_f, G4, G4);
  k_gemm_mfma<<<dim3(G4 / 64, Mp / 128), 256, 0, stream>>>(
      xh, WxT_b, Ep, Ep, nullptr, nullptr, 0, 0, b_b, nullptr, xp_b, G4, G4);
  // 2) BiLSTM (writes bf16 facts)
  k_lstm<<<dim3(B, 2), 512, 0, stream>>>(xp_f, xp_b, PAQ_f, PBQ_f, PAQ_b, PBQ_b, lengths, factsh);
  // 3) hop-invariant precomputes (MFMA); xr/xc overwrite xp_f, za/zb overwrite xp_b
  k_gemm_mfma<<<dim3(D / 64, Mp / 128), 256, 0, stream>>>(
      factsh, WrT, D, D, nullptr, nullptr, 0, 0, nullptr, nullptr, xr, D, D);
  k_gemm_mfma<<<dim3(D / 64, Mp / 128), 256, 0, stream>>>(
      factsh, WcT, D, D, nullptr, nullptr, 0, 0, nullptr, nullptr, xc, D, D);
  k_buildz<<<BT, 512, 0, stream>>>(factsh, q, za, zb);
  k_gemm_mfma<<<dim3(Ep / 64, Mp / 128), 256, 0, stream>>>(
      za, W1T[0], D, D, zb, W1T[2], D, D, b1, nullptr, part0, E, E);

  // 4) hops
  const float* m_in = q;
  float* mb[2] = {m0, m1};
  for (int i = 0; i < NH; ++i) {
    k_buildz<<<BT, 512, 0, stream>>>(factsh, m_in, za, zb);
    k_gemm_mfma<<<dim3(Ep / 64, Mp / 128), 256, 0, stream>>>(
        za, W1T[1], D, D, zb, W1T[3], D, D, nullptr, part0, att_h, E, E);
    k_score<<<BT, 64, 0, stream>>>(att_h, W2, b2, scores);
    k_softmax<<<B, 128, 0, stream>>>(scores, lengths, att);
    k_gru<<<B, 512, 0, stream>>>(xr, xc, UPQ, br, bc, att, lengths, epb);
    k_hop<<<B, 512, 0, stream>>>(m_in, epb, q,
                                 W_hops + (size_t)i * 3 * D * D, b_hops + (size_t)i * D,
                                 mb[i & 1]);
    m_in = mb[i & 1];
  }
  // 5) output
  k_out<<<B, 256, 0, stream>>>(m_in, q, Wo, bo, (float*)d_out);
}

// Round 7
// 4449.183 us; speedup vs baseline: 3.4454x; 1.0046x over previous
//
#include <hip/hip_runtime.h>

constexpr int B  = 64;
constexpr int T  = 121;
constexpr int E  = 300;
constexpr int Ep = 320;    // E padded to K-chunk multiple
constexpr int H  = 256;
constexpr int G4 = 1024;   // 4*H
constexpr int D  = 512;    // 2*H
constexpr int NH = 3;
constexpr int BT = B * T;  // 7744
constexpr int Mp = 7808;   // 61*128, M padded for 128-row tiles

using short8 = __attribute__((ext_vector_type(8))) short;
using f32x4  = __attribute__((ext_vector_type(4))) float;

__device__ __forceinline__ float sigmoidf(float x) { return 1.0f / (1.0f + __expf(-x)); }
__device__ __forceinline__ float tanhf_fast(float x) {
  float e = __expf(2.0f * x);
  return 1.0f - 2.0f / (e + 1.0f);
}
__device__ __forceinline__ unsigned bf16rne(float x) {
  unsigned u = __float_as_uint(x);
  return (u + 0x7fffu + ((u >> 16) & 1u)) >> 16;
}
__device__ __forceinline__ float bf_lo(unsigned u) { return __uint_as_float(u << 16); }
__device__ __forceinline__ float bf_hi(unsigned u) { return __uint_as_float(u & 0xffff0000u); }
__device__ __forceinline__ float bfu(unsigned short u) { return __uint_as_float(((unsigned)u) << 16); }

// ---------------- weight packing ----------------
// LSTM: bf16 pair-packed, uint4-grouped (round-4 verified)
__global__ void k_pack_lstm(const float* __restrict__ Wh,
                            uint4* __restrict__ PAQ, uint4* __restrict__ PBQ) {
  int idx = blockIdx.x * 256 + threadIdx.x;   // over (H/4)*256 = 16384
  int k4 = idx >> 8, j = idx & 255;
  int k = 4 * k4;
  uint4 a, bq;
  const float* r0 = Wh + (size_t)(k + 0) * G4;
  const float* r1 = Wh + (size_t)(k + 1) * G4;
  const float* r2 = Wh + (size_t)(k + 2) * G4;
  const float* r3 = Wh + (size_t)(k + 3) * G4;
  a.x  = bf16rne(r0[j]) | (bf16rne(r0[j + 256]) << 16);
  a.y  = bf16rne(r1[j]) | (bf16rne(r1[j + 256]) << 16);
  a.z  = bf16rne(r2[j]) | (bf16rne(r2[j + 256]) << 16);
  a.w  = bf16rne(r3[j]) | (bf16rne(r3[j + 256]) << 16);
  bq.x = bf16rne(r0[j + 512]) | (bf16rne(r0[j + 768]) << 16);
  bq.y = bf16rne(r1[j + 512]) | (bf16rne(r1[j + 768]) << 16);
  bq.z = bf16rne(r2[j + 512]) | (bf16rne(r2[j + 768]) << 16);
  bq.w = bf16rne(r3[j + 512]) | (bf16rne(r3[j + 768]) << 16);
  PAQ[idx] = a;
  PBQ[idx] = bq;
}

// generic B^T bf16 pack with zero padding: WT[n*Kpad + k] = bf16(W[k*stride + n]) or 0
__global__ void k_packT(const float* __restrict__ W, unsigned short* __restrict__ WT,
                        int Ksrc, int Nsrc, int stride, int Kpad) {
  int idx = blockIdx.x * 256 + threadIdx.x;
  int n = idx / Kpad, k = idx - n * Kpad;
  float v = (k < Ksrc && n < Nsrc) ? W[(size_t)k * stride + n] : 0.0f;
  WT[idx] = (unsigned short)bf16rne(v);
}

// ---------------- embedding gather -> bf16, K-padded ----------------
__global__ void k_gather(const int* __restrict__ tokens, const float* __restrict__ emb,
                         unsigned short* __restrict__ xh) {
  int bt = blockIdx.x;
  int tok = tokens[bt];
  const float* src = emb + (size_t)tok * E;
  unsigned short* dst = xh + (size_t)bt * Ep;
  for (int e = threadIdx.x; e < Ep; e += 256)
    dst[e] = (e < E) ? (unsigned short)bf16rne(src[e]) : (unsigned short)0;
}

// ---------------- bf16 MFMA GEMM (round-6 verified) ----------------
__global__ __launch_bounds__(256) void k_gemm_mfma(
    const unsigned short* __restrict__ A1, const unsigned short* __restrict__ B1, int K1, int lda1,
    const unsigned short* __restrict__ A2, const unsigned short* __restrict__ B2, int K2, int lda2,
    const float* __restrict__ bias, const float* __restrict__ Cin,
    float* __restrict__ C, int Nreal, int Cstride)
{
  __shared__ unsigned short As[128][40];
  __shared__ unsigned short Bs[64][40];
  int tid = threadIdx.x;
  int l = tid & 63, w = tid >> 6;
  int row0 = blockIdx.y * 128, col0 = blockIdx.x * 64;
  int lrow = l & 15, lk = (l >> 4) * 8, lq = (l >> 4) * 4;
  int ar = tid >> 1, asg = (tid & 1) * 16;
  int br = tid >> 2, bsg = (tid & 3) * 8;
  f32x4 acc[2][4] = {};
#pragma unroll 1
  for (int pass = 0; pass < 2; ++pass) {
    const unsigned short* A  = pass ? A2 : A1;
    const unsigned short* Bt = pass ? B2 : B1;
    int K   = pass ? K2 : K1;
    int lda = pass ? lda2 : lda1;
    if (K == 0) break;
    for (int k0 = 0; k0 < K; k0 += 32) {
      const uint4* ga = (const uint4*)(A + (size_t)(row0 + ar) * lda + k0 + asg);
      uint4 a0 = ga[0], a1 = ga[1];
      uint4 b0 = *(const uint4*)(Bt + (size_t)(col0 + br) * K + k0 + bsg);
      __syncthreads();
      *(uint4*)&As[ar][asg]     = a0;
      *(uint4*)&As[ar][asg + 8] = a1;
      *(uint4*)&Bs[br][bsg]     = b0;
      __syncthreads();
      short8 av[2], bv[4];
#pragma unroll
      for (int f = 0; f < 2; ++f)
        av[f] = *(const short8*)&As[w * 32 + f * 16 + lrow][lk];
#pragma unroll
      for (int fc = 0; fc < 4; ++fc)
        bv[fc] = *(const short8*)&Bs[fc * 16 + lrow][lk];
#pragma unroll
      for (int f = 0; f < 2; ++f)
#pragma unroll
        for (int fc = 0; fc < 4; ++fc)
          acc[f][fc] = __builtin_amdgcn_mfma_f32_16x16x32_bf16(av[f], bv[fc], acc[f][fc], 0, 0, 0);
    }
  }
#pragma unroll
  for (int f = 0; f < 2; ++f) {
#pragma unroll
    for (int fc = 0; fc < 4; ++fc) {
      int c = col0 + fc * 16 + lrow;
      if (c < Nreal) {
        float bb = bias ? bias[c] : 0.0f;
#pragma unroll
        for (int i = 0; i < 4; ++i) {
          int r = row0 + w * 32 + f * 16 + lq + i;
          if (r < BT) {
            float v = acc[f][fc][i] + bb;
            if (Cin) v += Cin[(size_t)r * Cstride + c];
            C[(size_t)r * Cstride + c] = v;
          }
        }
      }
    }
  }
}

// ---------------- BiLSTM scan (round-6 verified) ----------------
__global__ __launch_bounds__(512) void k_lstm(
    const float* __restrict__ xp_f, const float* __restrict__ xp_b,
    const uint4* __restrict__ PAQ_f, const uint4* __restrict__ PBQ_f,
    const uint4* __restrict__ PAQ_b, const uint4* __restrict__ PBQ_b,
    const int* __restrict__ lengths, unsigned short* __restrict__ factsh)
{
  int b = blockIdx.x;
  int dir = blockIdx.y;
  const float* xp = dir ? xp_b : xp_f;
  const uint4* PAQ = dir ? PAQ_b : PAQ_f;
  const uint4* PBQ = dir ? PBQ_b : PBQ_f;
  int tid = threadIdx.x;
  int j = tid & 255, half = tid >> 8;
  __shared__ float hs[H];
  __shared__ float4 red[512];
  hs[j] = 0.0f;
  float c = 0.0f, h = 0.0f;
  int nsteps = dir ? T : lengths[b];
  const uint4* pa = PAQ + (size_t)(half * 32) * 256 + j;
  const uint4* pb = PBQ + (size_t)(half * 32) * 256 + j;
  const float4* hs4 = reinterpret_cast<const float4*>(hs) + half * 32;
  __syncthreads();
  for (int s = 0; s < nsteps; ++s) {
    int t = dir ? (T - 1 - s) : s;
    float g0 = 0.f, g1 = 0.f, g2 = 0.f, g3 = 0.f;
#pragma unroll 4
    for (int k4 = 0; k4 < 32; ++k4) {
      uint4 a  = pa[(size_t)k4 * 256];
      uint4 bq = pb[(size_t)k4 * 256];
      float4 hv = hs4[k4];
      g0 = fmaf(hv.x, bf_lo(a.x), g0);  g1 = fmaf(hv.x, bf_hi(a.x), g1);
      g2 = fmaf(hv.x, bf_lo(bq.x), g2); g3 = fmaf(hv.x, bf_hi(bq.x), g3);
      g0 = fmaf(hv.y, bf_lo(a.y), g0);  g1 = fmaf(hv.y, bf_hi(a.y), g1);
      g2 = fmaf(hv.y, bf_lo(bq.y), g2); g3 = fmaf(hv.y, bf_hi(bq.y), g3);
      g0 = fmaf(hv.z, bf_lo(a.z), g0);  g1 = fmaf(hv.z, bf_hi(a.z), g1);
      g2 = fmaf(hv.z, bf_lo(bq.z), g2); g3 = fmaf(hv.z, bf_hi(bq.z), g3);
      g0 = fmaf(hv.w, bf_lo(a.w), g0);  g1 = fmaf(hv.w, bf_hi(a.w), g1);
      g2 = fmaf(hv.w, bf_lo(bq.w), g2); g3 = fmaf(hv.w, bf_hi(bq.w), g3);
    }
    red[tid] = make_float4(g0, g1, g2, g3);
    __syncthreads();
    if (half == 0) {
      float4 o = red[tid + 256];
      const float* xrow = xp + (size_t)(b * T + t) * G4;
      g0 += o.x + xrow[j];
      g1 += o.y + xrow[j + 256];
      g2 += o.z + xrow[j + 512];
      g3 += o.w + xrow[j + 768];
      float ig = sigmoidf(g0);
      float fg = sigmoidf(g1);
      float gg = tanhf_fast(g2);
      float og = sigmoidf(g3);
      c = fg * c + ig * gg;
      h = og * tanhf_fast(c);
      hs[j] = h;
      factsh[(size_t)(b * T + t) * D + dir * H + j] = (unsigned short)bf16rne(h);
    }
    __syncthreads();
  }
}

// ---------------- z halves -> bf16 ----------------
__global__ void k_buildz(const unsigned short* __restrict__ factsh, const float* __restrict__ v,
                         unsigned short* __restrict__ za, unsigned short* __restrict__ zb) {
  int bt = blockIdx.x;
  int b = bt / T;
  int d = threadIdx.x;  // 512
  float f = bfu(factsh[(size_t)bt * D + d]);
  float vv = v[(size_t)b * D + d];
  za[(size_t)bt * D + d] = (unsigned short)bf16rne(f * vv);
  zb[(size_t)bt * D + d] = (unsigned short)bf16rne(fabsf(f - vv));
}

// ---------------- score ----------------
__global__ void k_score(const float* __restrict__ att_h, const float* __restrict__ W2,
                        const float* __restrict__ b2, float* __restrict__ s) {
  int bt = blockIdx.x;
  int tid = threadIdx.x;  // 64
  float acc = 0.f;
  for (int e = tid; e < E; e += 64)
    acc += tanhf_fast(att_h[(size_t)bt * E + e]) * W2[e];
  for (int off = 32; off > 0; off >>= 1) acc += __shfl_down(acc, off);
  if (tid == 0) s[bt] = acc + b2[0];
}

// ---------------- masked softmax ----------------
__global__ void k_softmax(const float* __restrict__ s, const int* __restrict__ lengths,
                          float* __restrict__ a) {
  int b = blockIdx.x;
  int t = threadIdx.x;  // 128
  int len = lengths[b];
  __shared__ float wred[2];
  float val = -1e30f;
  if (t < T) val = (t < len) ? s[b * T + t] : -1e9f;
  float mx = val;
  for (int off = 32; off > 0; off >>= 1) mx = fmaxf(mx, __shfl_xor(mx, off));
  int wid = t >> 6, lane = t & 63;
  if (lane == 0) wred[wid] = mx;
  __syncthreads();
  mx = fmaxf(wred[0], wred[1]);
  __syncthreads();
  float e = (t < T && t < len) ? __expf(val - mx) : 0.0f;
  float sum = e;
  for (int off = 32; off > 0; off >>= 1) sum += __shfl_xor(sum, off);
  if (lane == 0) wred[wid] = sum;
  __syncthreads();
  float tot = wred[0] + wred[1];
  if (t < T) a[b * T + t] = e / tot;
}

// ---------------- GRU init: h = 0 (f32 + bf16 mirrors) ----------------
__global__ void k_ginit(float* __restrict__ Hf, unsigned short* __restrict__ Hb) {
  int i = blockIdx.x * 512 + threadIdx.x;
  Hf[i] = 0.0f;
  Hb[i] = 0;
}

// ---------------- per-step GRU GEMM+gate: one launch per timestep ----------------
// 16 blocks x 256 thr. Block bi owns h-cols [bi*32, bi*32+32).
// B-tile rows 0..31 = UrT rows j0..j0+31; rows 32..63 = UcT rows j0..j0+31.
// racc at frag fc(0,1) and cacc at frag fc+2 land in the same thread/reg -> fused gate.
__global__ __launch_bounds__(256) void k_gru_step(
    const unsigned short* __restrict__ Hb, float* __restrict__ Hf,
    unsigned short* __restrict__ HbOut,
    const unsigned short* __restrict__ URCT,   // [1024][512] bf16: UrT | UcT
    const float* __restrict__ xr, const float* __restrict__ xc,
    const float* __restrict__ br, const float* __restrict__ bc,
    const float* __restrict__ att, int t)
{
  __shared__ unsigned short As[64][40];
  __shared__ unsigned short Bs[64][40];
  int tid = threadIdx.x;
  int l = tid & 63, w = tid >> 2 >> 4;          // wave id 0..3
  int lrow = l & 15, lk = (l >> 4) * 8, lq = (l >> 4) * 4;
  int j0 = blockIdx.x * 32;
  int sr = tid >> 2, sg = (tid & 3) * 8;        // staging: row 0..63, 8-bf16 seg
  int bgrow = (sr < 32) ? (j0 + sr) : (512 + j0 + (sr - 32));
  f32x4 acc[4] = {};
  for (int k0 = 0; k0 < D; k0 += 32) {
    uint4 a0 = *(const uint4*)(Hb + (size_t)sr * D + k0 + sg);
    uint4 b0 = *(const uint4*)(URCT + (size_t)bgrow * D + k0 + sg);
    __syncthreads();
    *(uint4*)&As[sr][sg] = a0;
    *(uint4*)&Bs[sr][sg] = b0;
    __syncthreads();
    short8 av = *(const short8*)&As[w * 16 + lrow][lk];
    short8 bv[4];
#pragma unroll
    for (int fc = 0; fc < 4; ++fc)
      bv[fc] = *(const short8*)&Bs[fc * 16 + lrow][lk];
#pragma unroll
    for (int fc = 0; fc < 4; ++fc)
      acc[fc] = __builtin_amdgcn_mfma_f32_16x16x32_bf16(av, bv[fc], acc[fc], 0, 0, 0);
  }
  // epilogue: b = w*16 + lq + i ; j = j0 + fc*16 + lrow (fc 0,1); cacc at fc+2
#pragma unroll
  for (int fc = 0; fc < 2; ++fc) {
    int j = j0 + fc * 16 + lrow;
    float brj = br[j], bcj = bc[j];
#pragma unroll
    for (int i = 0; i < 4; ++i) {
      int b = w * 16 + lq + i;
      float g = att[b * T + t];
      size_t base = (size_t)(b * T + t) * D + j;
      float r  = sigmoidf(xr[base] + acc[fc][i] + brj);
      float hc = tanhf_fast(xc[base] + r * acc[fc + 2][i] + bcj);
      float hold = Hf[(size_t)b * D + j];
      float hnew = g * hc + (1.f - g) * hold;
      Hf[(size_t)b * D + j] = hnew;
      HbOut[(size_t)b * D + j] = (unsigned short)bf16rne(hnew);
    }
  }
}

// ---------------- hop projection ----------------
__global__ __launch_bounds__(512) void k_hop(
    const float* __restrict__ m_in, const float* __restrict__ ep,
    const float* __restrict__ q, const float* __restrict__ Whop,
    const float* __restrict__ bhop, float* __restrict__ m_out)
{
  int b = blockIdx.x, j = threadIdx.x;
  __shared__ float av[3 * D];
  av[j]         = m_in[(size_t)b * D + j];
  av[D + j]     = ep[(size_t)b * D + j];
  av[2 * D + j] = q[(size_t)b * D + j];
  __syncthreads();
  float acc = bhop[j];
#pragma unroll 4
  for (int k = 0; k < 3 * D; ++k)
    acc = fmaf(av[k], Whop[(size_t)k * D + j], acc);
  m_out[(size_t)b * D + j] = fmaxf(acc, 0.0f);
}

// ---------------- output ----------------
__global__ void k_out(const float* __restrict__ m, const float* __restrict__ q,
                      const float* __restrict__ Wo, const float* __restrict__ bo,
                      float* __restrict__ out)
{
  int b = blockIdx.x, tid = threadIdx.x;  // 256
  float acc = 0.f;
  for (int k = tid; k < D; k += 256)
    acc += m[(size_t)b * D + k] * Wo[k] + q[(size_t)b * D + k] * Wo[D + k];
  for (int off = 32; off > 0; off >>= 1) acc += __shfl_down(acc, off);
  __shared__ float red[4];
  int wid = tid >> 6, lane = tid & 63;
  if (lane == 0) red[wid] = acc;
  __syncthreads();
  if (tid == 0) {
    float tot = red[0] + red[1] + red[2] + red[3];
    out[b] = 1.0f / (1.0f + __expf(-(tot + bo[0])));
  }
}

extern "C" void kernel_launch(void* const* d_in, const int* in_sizes, int n_in,
                              void* d_out, int out_size, void* d_ws, size_t ws_size,
                              hipStream_t stream)
{
  const int*   tokens  = (const int*)d_in[0];
  const int*   lengths = (const int*)d_in[1];
  const float* emb     = (const float*)d_in[2];
  const float* Wx_f    = (const float*)d_in[3];
  const float* Wh_f    = (const float*)d_in[4];
  const float* b_f     = (const float*)d_in[5];
  const float* Wx_b    = (const float*)d_in[6];
  const float* Wh_b    = (const float*)d_in[7];
  const float* b_b     = (const float*)d_in[8];
  const float* W1      = (const float*)d_in[9];
  const float* b1      = (const float*)d_in[10];
  const float* W2      = (const float*)d_in[11];
  const float* b2      = (const float*)d_in[12];
  const float* Wr      = (const float*)d_in[13];
  const float* Ur      = (const float*)d_in[14];
  const float* br      = (const float*)d_in[15];
  const float* Wc      = (const float*)d_in[16];
  const float* Uc      = (const float*)d_in[17];
  const float* bc      = (const float*)d_in[18];
  const float* q       = (const float*)d_in[19];
  const float* W_hops  = (const float*)d_in[20];
  const float* b_hops  = (const float*)d_in[21];
  const float* Wo      = (const float*)d_in[22];
  const float* bo      = (const float*)d_in[23];
  float* ws = (float*)d_ws;

  // ---- workspace layout ----
  float* p = ws;
  unsigned short* xh = (unsigned short*)p;  p += (size_t)Mp * Ep / 2;
  float* xp_f   = p;  p += (size_t)BT * G4;                                 // later: xr | xc
  float* xp_b   = p;  p += (size_t)BT * G4;                                 // later: za | zb
  unsigned short* factsh = (unsigned short*)p;  p += (size_t)Mp * D / 2;
  float* att_h  = p;  p += (size_t)BT * E;
  float* part0  = p;  p += (size_t)BT * E;
  float* scores = p;  p += BT;
  float* att    = p;  p += BT;
  float* m0     = p;  p += (size_t)B * D;
  float* m1     = p;  p += (size_t)B * D;
  float* Hf     = p;  p += (size_t)B * D;           // GRU h state f32
  unsigned short* Hb = (unsigned short*)p;  p += (size_t)B * D / 2;  // bf16 mirror
  uint4* PAQ_f  = (uint4*)p;  p += (size_t)(H / 4) * 256 * 4;
  uint4* PBQ_f  = (uint4*)p;  p += (size_t)(H / 4) * 256 * 4;
  uint4* PAQ_b  = (uint4*)p;  p += (size_t)(H / 4) * 256 * 4;
  uint4* PBQ_b  = (uint4*)p;  p += (size_t)(H / 4) * 256 * 4;
  unsigned short* WxT_f = (unsigned short*)p;  p += (size_t)G4 * Ep / 2;
  unsigned short* WxT_b = (unsigned short*)p;  p += (size_t)G4 * Ep / 2;
  unsigned short* WrT   = (unsigned short*)p;  p += (size_t)D * D / 2;
  unsigned short* WcT   = (unsigned short*)p;  p += (size_t)D * D / 2;
  unsigned short* URCT  = (unsigned short*)p;  p += (size_t)(2 * D) * D / 2; // [1024][512]
  unsigned short* W1T[4];
  for (int c = 0; c < 4; ++c) { W1T[c] = (unsigned short*)p; p += (size_t)Ep * D / 2; }
  float* xr = xp_f;
  float* xc = xp_f + (size_t)BT * D;
  unsigned short* za = (unsigned short*)xp_b;
  unsigned short* zb = (unsigned short*)xp_b + (size_t)Mp * D;

  // 0) pack weights
  k_pack_lstm<<<(H / 4) * 256 / 256, 256, 0, stream>>>(Wh_f, PAQ_f, PBQ_f);
  k_pack_lstm<<<(H / 4) * 256 / 256, 256, 0, stream>>>(Wh_b, PAQ_b, PBQ_b);
  k_packT<<<G4 * Ep / 256, 256, 0, stream>>>(Wx_f, WxT_f, E, G4, G4, Ep);
  k_packT<<<G4 * Ep / 256, 256, 0, stream>>>(Wx_b, WxT_b, E, G4, G4, Ep);
  k_packT<<<D * D / 256, 256, 0, stream>>>(Wr, WrT, D, D, D, D);
  k_packT<<<D * D / 256, 256, 0, stream>>>(Wc, WcT, D, D, D, D);
  k_packT<<<D * D / 256, 256, 0, stream>>>(Ur, URCT, D, D, D, D);
  k_packT<<<D * D / 256, 256, 0, stream>>>(Uc, URCT + (size_t)D * D, D, D, D, D);
  for (int c = 0; c < 4; ++c)
    k_packT<<<Ep * D / 256, 256, 0, stream>>>(W1 + (size_t)c * D * E, W1T[c], D, E, E, D);

  // 1) embed + input projections (MFMA)
  k_gather<<<BT, 256, 0, stream>>>(tokens, emb, xh);
  k_gemm_mfma<<<dim3(G4 / 64, Mp / 128), 256, 0, stream>>>(
      xh, WxT_f, Ep, Ep, nullptr, nullptr, 0, 0, b_f, nullptr, xp_f, G4, G4);
  k_gemm_mfma<<<dim3(G4 / 64, Mp / 128), 256, 0, stream>>>(
      xh, WxT_b, Ep, Ep, nullptr, nullptr, 0, 0, b_b, nullptr, xp_b, G4, G4);
  // 2) BiLSTM
  k_lstm<<<dim3(B, 2), 512, 0, stream>>>(xp_f, xp_b, PAQ_f, PBQ_f, PAQ_b, PBQ_b, lengths, factsh);
  // 3) hop-invariant precomputes (MFMA)
  k_gemm_mfma<<<dim3(D / 64, Mp / 128), 256, 0, stream>>>(
      factsh, WrT, D, D, nullptr, nullptr, 0, 0, nullptr, nullptr, xr, D, D);
  k_gemm_mfma<<<dim3(D / 64, Mp / 128), 256, 0, stream>>>(
      factsh, WcT, D, D, nullptr, nullptr, 0, 0, nullptr, nullptr, xc, D, D);
  k_buildz<<<BT, 512, 0, stream>>>(factsh, q, za, zb);
  k_gemm_mfma<<<dim3(Ep / 64, Mp / 128), 256, 0, stream>>>(
      za, W1T[0], D, D, zb, W1T[2], D, D, b1, nullptr, part0, E, E);

  // 4) hops
  const float* m_in = q;
  float* mb[2] = {m0, m1};
  for (int i = 0; i < NH; ++i) {
    k_buildz<<<BT, 512, 0, stream>>>(factsh, m_in, za, zb);
    k_gemm_mfma<<<dim3(Ep / 64, Mp / 128), 256, 0, stream>>>(
        za, W1T[1], D, D, zb, W1T[3], D, D, nullptr, part0, att_h, E, E);
    k_score<<<BT, 64, 0, stream>>>(att_h, W2, b2, scores);
    k_softmax<<<B, 128, 0, stream>>>(scores, lengths, att);
    // GRU: 121 per-step GEMM+gate launches (cross-block h via stream ordering)
    k_ginit<<<B * D / 512, 512, 0, stream>>>(Hf, Hb);
    for (int t = 0; t < T; ++t)
      k_gru_step<<<16, 256, 0, stream>>>(Hb, Hf, Hb, URCT, xr, xc, br, bc, att, t);
    k_hop<<<B, 512, 0, stream>>>(m_in, Hf, q,
                                 W_hops + (size_t)i * 3 * D * D, b_hops + (size_t)i * D,
                                 mb[i & 1]);
    m_in = mb[i & 1];
  }
  // 5) output
  k_out<<<B, 256, 0, stream>>>(m_in, q, Wo, bo, (float*)d_out);
}

// Round 8
// 3418.560 us; speedup vs baseline: 4.4841x; 1.3015x over previous
//
#include <hip/hip_runtime.h>

constexpr int B  = 64;
constexpr int T  = 121;
constexpr int E  = 300;
constexpr int Ep = 320;    // E padded to K-chunk multiple
constexpr int H  = 256;
constexpr int G4 = 1024;   // 4*H
constexpr int D  = 512;    // 2*H
constexpr int NH = 3;
constexpr int BT = B * T;  // 7744
constexpr int Mp = 7808;   // 61*128, M padded for 128-row tiles

using short8 = __attribute__((ext_vector_type(8))) short;
using f32x4  = __attribute__((ext_vector_type(4))) float;

__device__ __forceinline__ float sigmoidf(float x) { return 1.0f / (1.0f + __expf(-x)); }
__device__ __forceinline__ float tanhf_fast(float x) {
  float e = __expf(2.0f * x);
  return 1.0f - 2.0f / (e + 1.0f);
}
__device__ __forceinline__ unsigned bf16rne(float x) {
  unsigned u = __float_as_uint(x);
  return (u + 0x7fffu + ((u >> 16) & 1u)) >> 16;
}
__device__ __forceinline__ float bf_lo(unsigned u) { return __uint_as_float(u << 16); }
__device__ __forceinline__ float bf_hi(unsigned u) { return __uint_as_float(u & 0xffff0000u); }
__device__ __forceinline__ float bfu(unsigned short u) { return __uint_as_float(((unsigned)u) << 16); }

// ---------------- weight packing ----------------
// LSTM: bf16 pair-packed, uint4-grouped (round-4 verified)
__global__ void k_pack_lstm(const float* __restrict__ Wh,
                            uint4* __restrict__ PAQ, uint4* __restrict__ PBQ) {
  int idx = blockIdx.x * 256 + threadIdx.x;   // over (H/4)*256 = 16384
  int k4 = idx >> 8, j = idx & 255;
  int k = 4 * k4;
  uint4 a, bq;
  const float* r0 = Wh + (size_t)(k + 0) * G4;
  const float* r1 = Wh + (size_t)(k + 1) * G4;
  const float* r2 = Wh + (size_t)(k + 2) * G4;
  const float* r3 = Wh + (size_t)(k + 3) * G4;
  a.x  = bf16rne(r0[j]) | (bf16rne(r0[j + 256]) << 16);
  a.y  = bf16rne(r1[j]) | (bf16rne(r1[j + 256]) << 16);
  a.z  = bf16rne(r2[j]) | (bf16rne(r2[j + 256]) << 16);
  a.w  = bf16rne(r3[j]) | (bf16rne(r3[j + 256]) << 16);
  bq.x = bf16rne(r0[j + 512]) | (bf16rne(r0[j + 768]) << 16);
  bq.y = bf16rne(r1[j + 512]) | (bf16rne(r1[j + 768]) << 16);
  bq.z = bf16rne(r2[j + 512]) | (bf16rne(r2[j + 768]) << 16);
  bq.w = bf16rne(r3[j + 512]) | (bf16rne(r3[j + 768]) << 16);
  PAQ[idx] = a;
  PBQ[idx] = bq;
}

// generic B^T bf16 pack with zero padding: WT[n*Kpad + k] = bf16(W[k*stride + n]) or 0
__global__ void k_packT(const float* __restrict__ W, unsigned short* __restrict__ WT,
                        int Ksrc, int Nsrc, int stride, int Kpad) {
  int idx = blockIdx.x * 256 + threadIdx.x;
  int n = idx / Kpad, k = idx - n * Kpad;
  float v = (k < Ksrc && n < Nsrc) ? W[(size_t)k * stride + n] : 0.0f;
  WT[idx] = (unsigned short)bf16rne(v);
}

// ---------------- embedding gather -> bf16, K-padded ----------------
__global__ void k_gather(const int* __restrict__ tokens, const float* __restrict__ emb,
                         unsigned short* __restrict__ xh) {
  int bt = blockIdx.x;
  int tok = tokens[bt];
  const float* src = emb + (size_t)tok * E;
  unsigned short* dst = xh + (size_t)bt * Ep;
  for (int e = threadIdx.x; e < Ep; e += 256)
    dst[e] = (e < E) ? (unsigned short)bf16rne(src[e]) : (unsigned short)0;
}

// ---------------- bf16 MFMA GEMM (round-6 verified) ----------------
__global__ __launch_bounds__(256) void k_gemm_mfma(
    const unsigned short* __restrict__ A1, const unsigned short* __restrict__ B1, int K1, int lda1,
    const unsigned short* __restrict__ A2, const unsigned short* __restrict__ B2, int K2, int lda2,
    const float* __restrict__ bias, const float* __restrict__ Cin,
    float* __restrict__ C, int Nreal, int Cstride)
{
  __shared__ unsigned short As[128][40];
  __shared__ unsigned short Bs[64][40];
  int tid = threadIdx.x;
  int l = tid & 63, w = tid >> 6;
  int row0 = blockIdx.y * 128, col0 = blockIdx.x * 64;
  int lrow = l & 15, lk = (l >> 4) * 8, lq = (l >> 4) * 4;
  int ar = tid >> 1, asg = (tid & 1) * 16;
  int br = tid >> 2, bsg = (tid & 3) * 8;
  f32x4 acc[2][4] = {};
#pragma unroll 1
  for (int pass = 0; pass < 2; ++pass) {
    const unsigned short* A  = pass ? A2 : A1;
    const unsigned short* Bt = pass ? B2 : B1;
    int K   = pass ? K2 : K1;
    int lda = pass ? lda2 : lda1;
    if (K == 0) break;
    for (int k0 = 0; k0 < K; k0 += 32) {
      const uint4* ga = (const uint4*)(A + (size_t)(row0 + ar) * lda + k0 + asg);
      uint4 a0 = ga[0], a1 = ga[1];
      uint4 b0 = *(const uint4*)(Bt + (size_t)(col0 + br) * K + k0 + bsg);
      __syncthreads();
      *(uint4*)&As[ar][asg]     = a0;
      *(uint4*)&As[ar][asg + 8] = a1;
      *(uint4*)&Bs[br][bsg]     = b0;
      __syncthreads();
      short8 av[2], bv[4];
#pragma unroll
      for (int f = 0; f < 2; ++f)
        av[f] = *(const short8*)&As[w * 32 + f * 16 + lrow][lk];
#pragma unroll
      for (int fc = 0; fc < 4; ++fc)
        bv[fc] = *(const short8*)&Bs[fc * 16 + lrow][lk];
#pragma unroll
      for (int f = 0; f < 2; ++f)
#pragma unroll
        for (int fc = 0; fc < 4; ++fc)
          acc[f][fc] = __builtin_amdgcn_mfma_f32_16x16x32_bf16(av[f], bv[fc], acc[f][fc], 0, 0, 0);
    }
  }
#pragma unroll
  for (int f = 0; f < 2; ++f) {
#pragma unroll
    for (int fc = 0; fc < 4; ++fc) {
      int c = col0 + fc * 16 + lrow;
      if (c < Nreal) {
        float bb = bias ? bias[c] : 0.0f;
#pragma unroll
        for (int i = 0; i < 4; ++i) {
          int r = row0 + w * 32 + f * 16 + lq + i;
          if (r < BT) {
            float v = acc[f][fc][i] + bb;
            if (Cin) v += Cin[(size_t)r * Cstride + c];
            C[(size_t)r * Cstride + c] = v;
          }
        }
      }
    }
  }
}

// ---------------- BiLSTM scan (round-6 verified) ----------------
__global__ __launch_bounds__(512) void k_lstm(
    const float* __restrict__ xp_f, const float* __restrict__ xp_b,
    const uint4* __restrict__ PAQ_f, const uint4* __restrict__ PBQ_f,
    const uint4* __restrict__ PAQ_b, const uint4* __restrict__ PBQ_b,
    const int* __restrict__ lengths, unsigned short* __restrict__ factsh)
{
  int b = blockIdx.x;
  int dir = blockIdx.y;
  const float* xp = dir ? xp_b : xp_f;
  const uint4* PAQ = dir ? PAQ_b : PAQ_f;
  const uint4* PBQ = dir ? PBQ_b : PBQ_f;
  int tid = threadIdx.x;
  int j = tid & 255, half = tid >> 8;
  __shared__ float hs[H];
  __shared__ float4 red[512];
  hs[j] = 0.0f;
  float c = 0.0f, h = 0.0f;
  int nsteps = dir ? T : lengths[b];
  const uint4* pa = PAQ + (size_t)(half * 32) * 256 + j;
  const uint4* pb = PBQ + (size_t)(half * 32) * 256 + j;
  const float4* hs4 = reinterpret_cast<const float4*>(hs) + half * 32;
  __syncthreads();
  for (int s = 0; s < nsteps; ++s) {
    int t = dir ? (T - 1 - s) : s;
    float g0 = 0.f, g1 = 0.f, g2 = 0.f, g3 = 0.f;
#pragma unroll 4
    for (int k4 = 0; k4 < 32; ++k4) {
      uint4 a  = pa[(size_t)k4 * 256];
      uint4 bq = pb[(size_t)k4 * 256];
      float4 hv = hs4[k4];
      g0 = fmaf(hv.x, bf_lo(a.x), g0);  g1 = fmaf(hv.x, bf_hi(a.x), g1);
      g2 = fmaf(hv.x, bf_lo(bq.x), g2); g3 = fmaf(hv.x, bf_hi(bq.x), g3);
      g0 = fmaf(hv.y, bf_lo(a.y), g0);  g1 = fmaf(hv.y, bf_hi(a.y), g1);
      g2 = fmaf(hv.y, bf_lo(bq.y), g2); g3 = fmaf(hv.y, bf_hi(bq.y), g3);
      g0 = fmaf(hv.z, bf_lo(a.z), g0);  g1 = fmaf(hv.z, bf_hi(a.z), g1);
      g2 = fmaf(hv.z, bf_lo(bq.z), g2); g3 = fmaf(hv.z, bf_hi(bq.z), g3);
      g0 = fmaf(hv.w, bf_lo(a.w), g0);  g1 = fmaf(hv.w, bf_hi(a.w), g1);
      g2 = fmaf(hv.w, bf_lo(bq.w), g2); g3 = fmaf(hv.w, bf_hi(bq.w), g3);
    }
    red[tid] = make_float4(g0, g1, g2, g3);
    __syncthreads();
    if (half == 0) {
      float4 o = red[tid + 256];
      const float* xrow = xp + (size_t)(b * T + t) * G4;
      g0 += o.x + xrow[j];
      g1 += o.y + xrow[j + 256];
      g2 += o.z + xrow[j + 512];
      g3 += o.w + xrow[j + 768];
      float ig = sigmoidf(g0);
      float fg = sigmoidf(g1);
      float gg = tanhf_fast(g2);
      float og = sigmoidf(g3);
      c = fg * c + ig * gg;
      h = og * tanhf_fast(c);
      hs[j] = h;
      factsh[(size_t)(b * T + t) * D + dir * H + j] = (unsigned short)bf16rne(h);
    }
    __syncthreads();
  }
}

// ---------------- z halves -> bf16 ----------------
__global__ void k_buildz(const unsigned short* __restrict__ factsh, const float* __restrict__ v,
                         unsigned short* __restrict__ za, unsigned short* __restrict__ zb) {
  int bt = blockIdx.x;
  int b = bt / T;
  int d = threadIdx.x;  // 512
  float f = bfu(factsh[(size_t)bt * D + d]);
  float vv = v[(size_t)b * D + d];
  za[(size_t)bt * D + d] = (unsigned short)bf16rne(f * vv);
  zb[(size_t)bt * D + d] = (unsigned short)bf16rne(fabsf(f - vv));
}

// ---------------- score ----------------
__global__ void k_score(const float* __restrict__ att_h, const float* __restrict__ W2,
                        const float* __restrict__ b2, float* __restrict__ s) {
  int bt = blockIdx.x;
  int tid = threadIdx.x;  // 64
  float acc = 0.f;
  for (int e = tid; e < E; e += 64)
    acc += tanhf_fast(att_h[(size_t)bt * E + e]) * W2[e];
  for (int off = 32; off > 0; off >>= 1) acc += __shfl_down(acc, off);
  if (tid == 0) s[bt] = acc + b2[0];
}

// ---------------- masked softmax ----------------
__global__ void k_softmax(const float* __restrict__ s, const int* __restrict__ lengths,
                          float* __restrict__ a) {
  int b = blockIdx.x;
  int t = threadIdx.x;  // 128
  int len = lengths[b];
  __shared__ float wred[2];
  float val = -1e30f;
  if (t < T) val = (t < len) ? s[b * T + t] : -1e9f;
  float mx = val;
  for (int off = 32; off > 0; off >>= 1) mx = fmaxf(mx, __shfl_xor(mx, off));
  int wid = t >> 6, lane = t & 63;
  if (lane == 0) wred[wid] = mx;
  __syncthreads();
  mx = fmaxf(wred[0], wred[1]);
  __syncthreads();
  float e = (t < T && t < len) ? __expf(val - mx) : 0.0f;
  float sum = e;
  for (int off = 32; off > 0; off >>= 1) sum += __shfl_xor(sum, off);
  if (lane == 0) wred[wid] = sum;
  __syncthreads();
  float tot = wred[0] + wred[1];
  if (t < T) a[b * T + t] = e / tot;
}

// ---------------- zero helpers ----------------
__global__ void k_zero(int* __restrict__ p, int n) {
  int i = blockIdx.x * blockDim.x + threadIdx.x;
  if (i < n) p[i] = 0;
}
__global__ void k_ginit(unsigned short* __restrict__ Hb0) {
  Hb0[blockIdx.x * 512 + threadIdx.x] = 0;
}

// ---------------- persistent GRU hop: 16 blocks, weights in LDS, grid barrier ------
// Block bi owns h-cols [bi*32, bi*32+32) for ALL 64 batches. LDS weight slice:
// rows 0..31 = UrT rows j0.., rows 32..63 = UcT rows j0.. ; 16B-unit XOR swizzle.
// h state in registers; Hb double-buffered bf16 (race-free); att==0 freezes masked steps.
__global__ __launch_bounds__(256) void k_gru_hop(
    const unsigned short* __restrict__ URCT,   // [1024][512] bf16: UrT | UcT
    unsigned short* __restrict__ Hb,           // [2][B][D] bf16, Hb[0] pre-zeroed
    float* __restrict__ ep,
    const float* __restrict__ xr, const float* __restrict__ xc,
    const float* __restrict__ br, const float* __restrict__ bc,
    const float* __restrict__ att, int* __restrict__ syncA)
{
  __shared__ unsigned short Wl[64 * 512];      // 64 KB
  const int tid = threadIdx.x;
  const int bi  = blockIdx.x;                  // 0..15
  const int j0  = bi * 32;
  const int l = tid & 63, w = tid >> 6;        // wave 0..3
  const int lrow = l & 15, g = l >> 4;         // g 0..3
  const int lq = g * 4;

  // load weight slice -> LDS (unit-XOR swizzle kills the 16-way read conflict)
  for (int it = tid; it < 64 * 64; it += 256) {
    int row = it >> 6, unit = it & 63;
    int grow = (row < 32) ? (j0 + row) : (512 + j0 + row - 32);
    uint4 v = *(const uint4*)(URCT + (size_t)grow * 512 + unit * 8);
    *(uint4*)&Wl[row * 512 + ((unit ^ (row & 7)) * 8)] = v;
  }
  __syncthreads();

  float h[2][4] = {};
  float brj[2], bcj[2];
#pragma unroll
  for (int fc = 0; fc < 2; ++fc) {
    brj[fc] = br[j0 + fc * 16 + lrow];
    bcj[fc] = bc[j0 + fc * 16 + lrow];
  }

  for (int t = 0; t < T; ++t) {
    const unsigned short* Hin = Hb + (size_t)(t & 1) * (B * D);
    unsigned short*      Hout = Hb + (size_t)((t + 1) & 1) * (B * D);
    // prefetch A fragments (row = batch w*16+lrow) and epilogue operands
    uint4 a[16];
#pragma unroll
    for (int c = 0; c < 16; ++c)
      a[c] = *(const uint4*)(Hin + (size_t)(w * 16 + lrow) * D + c * 32 + g * 8);
    float xrv[2][4], xcv[2][4], gv[4];
#pragma unroll
    for (int i = 0; i < 4; ++i) {
      int b = w * 16 + lq + i;
      gv[i] = att[b * T + t];
#pragma unroll
      for (int fc = 0; fc < 2; ++fc) {
        size_t base = (size_t)(b * T + t) * D + j0 + fc * 16 + lrow;
        xrv[fc][i] = xr[base];
        xcv[fc][i] = xc[base];
      }
    }
    f32x4 acc[4] = {};
#pragma unroll
    for (int c = 0; c < 16; ++c) {
      short8 av = *(const short8*)&a[c];
#pragma unroll
      for (int fc = 0; fc < 4; ++fc) {
        int row = fc * 16 + lrow;
        short8 bv = *(const short8*)&Wl[row * 512 + (((c * 4 + g) ^ (row & 7)) * 8)];
        acc[fc] = __builtin_amdgcn_mfma_f32_16x16x32_bf16(av, bv, acc[fc], 0, 0, 0);
      }
    }
    // fused gate epilogue: racc at frag fc, cacc at frag fc+2 (same lane/reg)
#pragma unroll
    for (int fc = 0; fc < 2; ++fc) {
#pragma unroll
      for (int i = 0; i < 4; ++i) {
        int b = w * 16 + lq + i;
        float r  = sigmoidf(xrv[fc][i] + acc[fc][i] + brj[fc]);
        float hc = tanhf_fast(xcv[fc][i] + r * acc[fc + 2][i] + bcj[fc]);
        float hn = gv[i] * hc + (1.f - gv[i]) * h[fc][i];
        h[fc][i] = hn;
        Hout[(size_t)b * D + j0 + fc * 16 + lrow] = (unsigned short)bf16rne(hn);
      }
    }
    // grid barrier (round-2-verified release/acquire pattern; weights fence-immune in LDS)
    __syncthreads();
    if (tid == 0) {
      __threadfence();
      atomicAdd(&syncA[t], 1);
      while (__hip_atomic_load(&syncA[t], __ATOMIC_RELAXED, __HIP_MEMORY_SCOPE_AGENT) < 16)
        __builtin_amdgcn_s_sleep(1);
    }
    __syncthreads();
    __threadfence();
  }
#pragma unroll
  for (int fc = 0; fc < 2; ++fc)
#pragma unroll
    for (int i = 0; i < 4; ++i) {
      int b = w * 16 + lq + i;
      ep[(size_t)b * D + j0 + fc * 16 + lrow] = h[fc][i];
    }
}

// ---------------- hop projection ----------------
__global__ __launch_bounds__(512) void k_hop(
    const float* __restrict__ m_in, const float* __restrict__ ep,
    const float* __restrict__ q, const float* __restrict__ Whop,
    const float* __restrict__ bhop, float* __restrict__ m_out)
{
  int b = blockIdx.x, j = threadIdx.x;
  __shared__ float av[3 * D];
  av[j]         = m_in[(size_t)b * D + j];
  av[D + j]     = ep[(size_t)b * D + j];
  av[2 * D + j] = q[(size_t)b * D + j];
  __syncthreads();
  float acc = bhop[j];
#pragma unroll 4
  for (int k = 0; k < 3 * D; ++k)
    acc = fmaf(av[k], Whop[(size_t)k * D + j], acc);
  m_out[(size_t)b * D + j] = fmaxf(acc, 0.0f);
}

// ---------------- output ----------------
__global__ void k_out(const float* __restrict__ m, const float* __restrict__ q,
                      const float* __restrict__ Wo, const float* __restrict__ bo,
                      float* __restrict__ out)
{
  int b = blockIdx.x, tid = threadIdx.x;  // 256
  float acc = 0.f;
  for (int k = tid; k < D; k += 256)
    acc += m[(size_t)b * D + k] * Wo[k] + q[(size_t)b * D + k] * Wo[D + k];
  for (int off = 32; off > 0; off >>= 1) acc += __shfl_down(acc, off);
  __shared__ float red[4];
  int wid = tid >> 6, lane = tid & 63;
  if (lane == 0) red[wid] = acc;
  __syncthreads();
  if (tid == 0) {
    float tot = red[0] + red[1] + red[2] + red[3];
    out[b] = 1.0f / (1.0f + __expf(-(tot + bo[0])));
  }
}

extern "C" void kernel_launch(void* const* d_in, const int* in_sizes, int n_in,
                              void* d_out, int out_size, void* d_ws, size_t ws_size,
                              hipStream_t stream)
{
  const int*   tokens  = (const int*)d_in[0];
  const int*   lengths = (const int*)d_in[1];
  const float* emb     = (const float*)d_in[2];
  const float* Wx_f    = (const float*)d_in[3];
  const float* Wh_f    = (const float*)d_in[4];
  const float* b_f     = (const float*)d_in[5];
  const float* Wx_b    = (const float*)d_in[6];
  const float* Wh_b    = (const float*)d_in[7];
  const float* b_b     = (const float*)d_in[8];
  const float* W1      = (const float*)d_in[9];
  const float* b1      = (const float*)d_in[10];
  const float* W2      = (const float*)d_in[11];
  const float* b2      = (const float*)d_in[12];
  const float* Wr      = (const float*)d_in[13];
  const float* Ur      = (const float*)d_in[14];
  const float* br      = (const float*)d_in[15];
  const float* Wc      = (const float*)d_in[16];
  const float* Uc      = (const float*)d_in[17];
  const float* bc      = (const float*)d_in[18];
  const float* q       = (const float*)d_in[19];
  const float* W_hops  = (const float*)d_in[20];
  const float* b_hops  = (const float*)d_in[21];
  const float* Wo      = (const float*)d_in[22];
  const float* bo      = (const float*)d_in[23];
  float* ws = (float*)d_ws;

  // ---- workspace layout ----
  float* p = ws;
  unsigned short* xh = (unsigned short*)p;  p += (size_t)Mp * Ep / 2;
  float* xp_f   = p;  p += (size_t)BT * G4;                                 // later: xr | xc
  float* xp_b   = p;  p += (size_t)BT * G4;                                 // later: za | zb
  unsigned short* factsh = (unsigned short*)p;  p += (size_t)Mp * D / 2;
  float* att_h  = p;  p += (size_t)BT * E;
  float* part0  = p;  p += (size_t)BT * E;
  float* scores = p;  p += BT;
  float* att    = p;  p += BT;
  float* m0     = p;  p += (size_t)B * D;
  float* m1     = p;  p += (size_t)B * D;
  float* epb    = p;  p += (size_t)B * D;
  unsigned short* Hb = (unsigned short*)p;  p += (size_t)2 * B * D / 2;     // [2][B][D] bf16
  int* syncA    = (int*)p;  p += 3 * 128;
  uint4* PAQ_f  = (uint4*)p;  p += (size_t)(H / 4) * 256 * 4;
  uint4* PBQ_f  = (uint4*)p;  p += (size_t)(H / 4) * 256 * 4;
  uint4* PAQ_b  = (uint4*)p;  p += (size_t)(H / 4) * 256 * 4;
  uint4* PBQ_b  = (uint4*)p;  p += (size_t)(H / 4) * 256 * 4;
  unsigned short* WxT_f = (unsigned short*)p;  p += (size_t)G4 * Ep / 2;
  unsigned short* WxT_b = (unsigned short*)p;  p += (size_t)G4 * Ep / 2;
  unsigned short* WrT   = (unsigned short*)p;  p += (size_t)D * D / 2;
  unsigned short* WcT   = (unsigned short*)p;  p += (size_t)D * D / 2;
  unsigned short* URCT  = (unsigned short*)p;  p += (size_t)(2 * D) * D / 2; // [1024][512]
  unsigned short* W1T[4];
  for (int c = 0; c < 4; ++c) { W1T[c] = (unsigned short*)p; p += (size_t)Ep * D / 2; }
  float* xr = xp_f;
  float* xc = xp_f + (size_t)BT * D;
  unsigned short* za = (unsigned short*)xp_b;
  unsigned short* zb = (unsigned short*)xp_b + (size_t)Mp * D;

  // 0) zero barrier counters + pack weights
  k_zero<<<1, 384, 0, stream>>>(syncA, 3 * 128);
  k_pack_lstm<<<(H / 4) * 256 / 256, 256, 0, stream>>>(Wh_f, PAQ_f, PBQ_f);
  k_pack_lstm<<<(H / 4) * 256 / 256, 256, 0, stream>>>(Wh_b, PAQ_b, PBQ_b);
  k_packT<<<G4 * Ep / 256, 256, 0, stream>>>(Wx_f, WxT_f, E, G4, G4, Ep);
  k_packT<<<G4 * Ep / 256, 256, 0, stream>>>(Wx_b, WxT_b, E, G4, G4, Ep);
  k_packT<<<D * D / 256, 256, 0, stream>>>(Wr, WrT, D, D, D, D);
  k_packT<<<D * D / 256, 256, 0, stream>>>(Wc, WcT, D, D, D, D);
  k_packT<<<D * D / 256, 256, 0, stream>>>(Ur, URCT, D, D, D, D);
  k_packT<<<D * D / 256, 256, 0, stream>>>(Uc, URCT + (size_t)D * D, D, D, D, D);
  for (int c = 0; c < 4; ++c)
    k_packT<<<Ep * D / 256, 256, 0, stream>>>(W1 + (size_t)c * D * E, W1T[c], D, E, E, D);

  // 1) embed + input projections (MFMA)
  k_gather<<<BT, 256, 0, stream>>>(tokens, emb, xh);
  k_gemm_mfma<<<dim3(G4 / 64, Mp / 128), 256, 0, stream>>>(
      xh, WxT_f, Ep, Ep, nullptr, nullptr, 0, 0, b_f, nullptr, xp_f, G4, G4);
  k_gemm_mfma<<<dim3(G4 / 64, Mp / 128), 256, 0, stream>>>(
      xh, WxT_b, Ep, Ep, nullptr, nullptr, 0, 0, b_b, nullptr, xp_b, G4, G4);
  // 2) BiLSTM
  k_lstm<<<dim3(B, 2), 512, 0, stream>>>(xp_f, xp_b, PAQ_f, PBQ_f, PAQ_b, PBQ_b, lengths, factsh);
  // 3) hop-invariant precomputes (MFMA)
  k_gemm_mfma<<<dim3(D / 64, Mp / 128), 256, 0, stream>>>(
      factsh, WrT, D, D, nullptr, nullptr, 0, 0, nullptr, nullptr, xr, D, D);
  k_gemm_mfma<<<dim3(D / 64, Mp / 128), 256, 0, stream>>>(
      factsh, WcT, D, D, nullptr, nullptr, 0, 0, nullptr, nullptr, xc, D, D);
  k_buildz<<<BT, 512, 0, stream>>>(factsh, q, za, zb);
  k_gemm_mfma<<<dim3(Ep / 64, Mp / 128), 256, 0, stream>>>(
      za, W1T[0], D, D, zb, W1T[2], D, D, b1, nullptr, part0, E, E);

  // 4) hops
  const float* m_in = q;
  float* mb[2] = {m0, m1};
  for (int i = 0; i < NH; ++i) {
    k_buildz<<<BT, 512, 0, stream>>>(factsh, m_in, za, zb);
    k_gemm_mfma<<<dim3(Ep / 64, Mp / 128), 256, 0, stream>>>(
        za, W1T[1], D, D, zb, W1T[3], D, D, nullptr, part0, att_h, E, E);
    k_score<<<BT, 64, 0, stream>>>(att_h, W2, b2, scores);
    k_softmax<<<B, 128, 0, stream>>>(scores, lengths, att);
    // GRU: single persistent kernel per hop
    k_ginit<<<B * D / 512, 512, 0, stream>>>(Hb);
    k_gru_hop<<<16, 256, 0, stream>>>(URCT, Hb, epb, xr, xc, br, bc, att, syncA + i * 128);
    k_hop<<<B, 512, 0, stream>>>(m_in, epb, q,
                                 W_hops + (size_t)i * 3 * D * D, b_hops + (size_t)i * D,
                                 mb[i & 1]);
    m_in = mb[i & 1];
  }
  // 5) output
  k_out<<<B, 256, 0, stream>>>(m_in, q, Wo, bo, (float*)d_out);
}